// Round 10
// baseline (237.951 us; speedup 1.0000x reference)
//
#include <hip/hip_runtime.h>
#include <stdint.h>

#define NTOK 1536
#define CDIM 768
#define NH 8
#define DKH 64
#define DVH 96
#define NF 96

typedef unsigned short u16;
typedef __attribute__((ext_vector_type(8))) short s16x8;   // 8 bf16 (4 VGPRs)
typedef __attribute__((ext_vector_type(4))) float f32x4;   // MFMA acc

#define LGKM0() asm volatile("s_waitcnt lgkmcnt(0)" ::: "memory")

__device__ __forceinline__ float b2f(u16 u) {
    union { uint32_t i; float f; } v; v.i = ((uint32_t)u) << 16; return v.f;
}
__device__ __forceinline__ u16 f2b(float f) {
    union { float f; uint32_t i; } v; v.f = f;
    uint32_t x = v.i;
    return (u16)((x + 0x7FFFu + ((x >> 16) & 1u)) >> 16);
}
__device__ __forceinline__ float ldin(const void* p, int i, int f32) {
    return f32 ? ((const float*)p)[i] : b2f(((const u16*)p)[i]);
}

// ---------------------------------------------------------------------------
// ws layout (float offsets). flags[0..8] at ws[0..8]. ~14.8 MB.
// ---------------------------------------------------------------------------
#define OFF_WSUF 16
#define OFF_S11  (OFF_WSUF + 5632)      // 5648
#define OFF_QC16 (OFF_S11 + 147456)     // u16[786432] bf16 (q/8 + rcb), (h,i,d)
#define OFF_KB16 (OFF_QC16 + 393216)    // u16[786432] bf16 k, (h,j,d)
#define OFF_VT16 (OFF_KB16 + 393216)    // u16[1179648] bf16 v^T, (h,d,j)
#define OFF_AOB  (OFF_VT16 + 589824)    // u16[1179648] bf16 attn out, (i, h*96+d)
#define OFF_XB16 (OFF_AOB + 589824)     // u16[1179648] bf16 x, (i,k)
#define OFF_WT   (OFF_XB16 + 589824)    // u16[1792*768] bf16 [Wq|Wk|Wv]^T, (n,k)
#define OFF_WOT  (OFF_WT + 688128)      // u16[589824] bf16 Wout^T, (n,k)
// end = 3,692,048 floats = 14.8 MB

struct In9 { const void* p[9]; int n[9]; };

// ---------------------------------------------------------------------------
// Kernel P: per-input dtype probe. flags[k]=1 iff fp32.
// ---------------------------------------------------------------------------
__global__ __launch_bounds__(256) void probe_all(In9 s, int* __restrict__ flags) {
    __shared__ int bad;
    int k = blockIdx.x;
    if (threadIdx.x == 0) bad = 0;
    __syncthreads();
    const u16* a = (const u16*)s.p[k];
    int n = s.n[k];
    if (n > 2048) n = 2048;
    int my = 0;
    for (int i = threadIdx.x; i < n; i += 256) {
        float v = b2f(a[i]);
        if (!(fabsf(v) < 1e6f)) my = 1;
    }
    if (my) atomicOr(&bad, 1);
    __syncthreads();
    if (threadIdx.x == 0) flags[k] = bad;
}

// ---------------------------------------------------------------------------
// Kernel 0: wsuf[t][hd] = sum_{f>=t} Wpos[f][hd], t<11 (validated collapse).
// ---------------------------------------------------------------------------
__global__ __launch_bounds__(512) void wsuf_k(const void* __restrict__ Wpos,
                                              int fi, float* __restrict__ ws) {
    int f32 = ((const int*)ws)[fi];
    int hd = threadIdx.x;
    int t = blockIdx.x;
    float s = 0.f;
    for (int f = t; f < NF; ++f) s += ldin(Wpos, f * 512 + hd, f32);
    ws[OFF_WSUF + t * 512 + hd] = s;
}

// ---------------------------------------------------------------------------
// Kernel T: transpose+convert weights to bf16 (n,k) layout.
//   blocks 0..335: wt (1792x768) from Wq|Wk|Wv;  336..479: wot from Wout.
// ---------------------------------------------------------------------------
__global__ __launch_bounds__(256) void prep_t(const void* __restrict__ Wq,
                                              const void* __restrict__ Wk,
                                              const void* __restrict__ Wv,
                                              const void* __restrict__ Wout,
                                              int fq, int fk, int fv, int fw,
                                              float* __restrict__ ws) {
    __shared__ float lds[64 * 65];
    const int* flags = (const int*)ws;
    u16* wt  = (u16*)(ws + OFF_WT);
    u16* wot = (u16*)(ws + OFF_WOT);

    int bx = blockIdx.x;
    const void* src; int ld, cn0, f, n0, k0; u16* dst;
    if (bx < 336) {
        int tn = bx / 12, tk = bx % 12;
        n0 = tn * 64; k0 = tk * 64;
        if (n0 < 512)       { src = Wq; ld = 512;  cn0 = n0;        f = flags[fq]; }
        else if (n0 < 1024) { src = Wk; ld = 512;  cn0 = n0 - 512;  f = flags[fk]; }
        else                { src = Wv; ld = CDIM; cn0 = n0 - 1024; f = flags[fv]; }
        dst = wt;
    } else {
        int b2 = bx - 336;
        int tn = b2 / 12, tk = b2 % 12;
        n0 = tn * 64; k0 = tk * 64;
        src = Wout; ld = CDIM; cn0 = n0; f = flags[fw];
        dst = wot;
    }
    int tid = threadIdx.x;
    for (int idx = tid; idx < 4096; idx += 256) {
        int r = idx >> 6, c = idx & 63;   // r=k_local, c=n_local
        lds[c * 65 + r] = ldin(src, (k0 + r) * ld + cn0 + c, f);
    }
    __syncthreads();
    for (int idx = tid; idx < 4096; idx += 256) {
        int r = idx >> 6, c = idx & 63;   // r=n_local, c=k_local
        dst[(n0 + r) * CDIM + k0 + c] = f2b(lds[r * 65 + c]);
    }
}

// ---------------------------------------------------------------------------
// Kernel X: x -> bf16 (i,k).
// ---------------------------------------------------------------------------
__global__ __launch_bounds__(256) void xconv(const void* __restrict__ x,
                                             int fx, float* __restrict__ ws) {
    int f32 = ((const int*)ws)[fx];
    u16* xb = (u16*)(ws + OFF_XB16);
    int i = (blockIdx.x * 256 + threadIdx.x) * 4;
    ushort4 o;
    if (f32) {
        float4 v = *(const float4*)((const float*)x + i);
        o.x = f2b(v.x); o.y = f2b(v.y); o.z = f2b(v.z); o.w = f2b(v.w);
    } else {
        o = *(const ushort4*)((const u16*)x + i);
    }
    *(ushort4*)(xb + i) = o;
}

// ---------------------------------------------------------------------------
// Kernel 1: QKV GEMM, register-direct MFMA (no LDS staging, no barriers).
// A-frags from xb16 (k-contig), B-frags from wt (k-contig).  s11+qc16 fused
// epilogue for Q tiles (one LDS round-trip + single barrier at end).
// ---------------------------------------------------------------------------
__global__ __launch_bounds__(256) void qkv_reg(const void* __restrict__ rcb,
                                               const void* __restrict__ rpb,
                                               int fc, int fp,
                                               float* __restrict__ ws) {
    __shared__ float qt[64 * 68];
    __shared__ float rpd[12];
    const int* flags = (const int*)ws;
    const u16* xb16 = (const u16*)(ws + OFF_XB16);
    const u16* wt   = (const u16*)(ws + OFF_WT);
    u16* qc16 = (u16*)(ws + OFF_QC16);
    u16* kb16 = (u16*)(ws + OFF_KB16);
    u16* vt16 = (u16*)(ws + OFF_VT16);

    int tid = threadIdx.x;
    int lane = tid & 63, w = tid >> 6;
    int quad = lane >> 4, col = lane & 15;
    int i0 = blockIdx.x * 64;
    int n0 = blockIdx.y * 64;
    bool isQ = (n0 < 512);
    int hq = n0 >> 6;

    if (isQ && tid < 12) {
        float s = 0.f;
        if (tid < 11) {
            const float* wp = ws + OFF_WSUF + tid * 512 + hq * 64;
            int f32p = flags[fp];
            for (int d = 0; d < 64; ++d) s += ldin(rpb, hq * 64 + d, f32p) * wp[d];
        }
        rpd[tid] = s;
    }

    f32x4 acc[4];
#pragma unroll
    for (int mt = 0; mt < 4; ++mt) acc[mt] = (f32x4){0.f, 0.f, 0.f, 0.f};

    const u16* brow = wt + (n0 + w * 16 + col) * CDIM + quad * 8;
#pragma unroll 2
    for (int k0 = 0; k0 < CDIM; k0 += 64) {
#pragma unroll
        for (int kc = 0; kc < 2; ++kc) {
            s16x8 bfrag = *(const s16x8*)(brow + k0 + kc * 32);
#pragma unroll
            for (int mt = 0; mt < 4; ++mt) {
                s16x8 afrag = *(const s16x8*)(xb16 + (i0 + mt * 16 + col) * CDIM
                                              + k0 + kc * 32 + quad * 8);
                acc[mt] = __builtin_amdgcn_mfma_f32_16x16x32_bf16(afrag, bfrag, acc[mt], 0, 0, 0);
            }
        }
    }

    if (isQ) {
#pragma unroll
        for (int mt = 0; mt < 4; ++mt)
#pragma unroll
            for (int r = 0; r < 4; ++r)
                qt[(mt * 16 + quad * 4 + r) * 68 + w * 16 + col] = acc[mt][r] * 0.125f;
        __syncthreads();
        int f32c = flags[fc];
        for (int idx = tid; idx < 64 * 64; idx += 256) {
            int row = idx >> 6, d = idx & 63;
            qc16[(hq * NTOK + i0 + row) * DKH + d] =
                f2b(qt[row * 68 + d] + ldin(rcb, hq * 64 + d, f32c));
        }
        const float* wsuf = ws + OFF_WSUF;
        float* s11 = ws + OFF_S11;
        for (int idx = tid; idx < 64 * 12; idx += 256) {
            int row = idx / 12, t = idx % 12;
            float s = rpd[t];
            if (t < 11) {
                const float* wp = wsuf + t * 512 + hq * 64;
                const float* qr = qt + row * 68;
                for (int d = 0; d < 64; ++d) s += qr[d] * wp[d];
            }
            s11[(hq * NTOK + i0 + row) * 12 + t] = s;
        }
    } else {
        int c = n0 + w * 16 + col;
#pragma unroll
        for (int mt = 0; mt < 4; ++mt) {
#pragma unroll
            for (int r = 0; r < 4; ++r) {
                int i = i0 + mt * 16 + quad * 4 + r;
                float val = acc[mt][r];
                if (c < 1024) {
                    int cc = c - 512;
                    int h = cc >> 6, d = cc & 63;
                    kb16[(h * NTOK + i) * DKH + d] = f2b(val);
                } else {
                    int cc = c - 1024;
                    int h = cc / 96, d = cc % 96;
                    vt16[(h * DVH + d) * NTOK + i] = f2b(val);
                }
            }
        }
    }
}

// ---------------------------------------------------------------------------
// Kernel 3: MFMA flash attention, fixed-offset softmax (exp(s-12); logits
// bounded |s|<~10 by construction -> shift-invariant softmax is exact).
// Grid 768 = 8 heads x 96 Q-tiles(16 rows); 4 waves split keys 384 each.
// No per-iter barriers: pbuf is per-wave, guarded by lgkmcnt fences.
// End: plain add-merge across waves (no max alignment needed).
// ---------------------------------------------------------------------------
__global__ __launch_bounds__(256) void attn_mfma(float* __restrict__ ws) {
    __shared__ float s11b[192];
    __shared__ alignas(16) u16 pbuf[4][2][16 * 36];
    __shared__ float Om[4][16 * 96];
    __shared__ float lw[4][16];

    const u16* qc16 = (const u16*)(ws + OFF_QC16);
    const u16* kb16 = (const u16*)(ws + OFF_KB16);
    const u16* vt16 = (const u16*)(ws + OFF_VT16);
    const float* s11 = ws + OFF_S11;
    u16* aob = (u16*)(ws + OFF_AOB);

    int h = blockIdx.x & 7;               // XCD-affine
    int i0 = (blockIdx.x >> 3) * 16;
    int tid = threadIdx.x;
    int wv = tid >> 6, lane = tid & 63;
    int quad = lane >> 4, col = lane & 15;

    if (tid < 192) s11b[tid] = s11[(h * NTOK + i0 + tid / 12) * 12 + tid % 12];
    const u16* qrow = qc16 + (h * NTOK + i0 + col) * DKH;
    s16x8 a_lo = *(const s16x8*)(qrow + quad * 8);
    s16x8 a_hi = *(const s16x8*)(qrow + 32 + quad * 8);
    __syncthreads();

    f32x4 O[2][6];
    float lsum[4];
#pragma unroll
    for (int s = 0; s < 2; ++s)
#pragma unroll
        for (int nt = 0; nt < 6; ++nt) O[s][nt] = (f32x4){0.f, 0.f, 0.f, 0.f};
#pragma unroll
    for (int r = 0; r < 4; ++r) lsum[r] = 0.f;

    for (int c = 0; c < 6; ++c) {
        f32x4 S[2][2];
        // ---- QK^T ----
#pragma unroll
        for (int s = 0; s < 2; ++s) {
            int j0 = wv * 384 + s * 192 + c * 32;
            const u16* k0p = kb16 + (h * NTOK + j0 + col) * DKH;
            const u16* k1p = kb16 + (h * NTOK + j0 + 16 + col) * DKH;
            s16x8 b0lo = *(const s16x8*)(k0p + quad * 8);
            s16x8 b0hi = *(const s16x8*)(k0p + 32 + quad * 8);
            s16x8 b1lo = *(const s16x8*)(k1p + quad * 8);
            s16x8 b1hi = *(const s16x8*)(k1p + 32 + quad * 8);
            f32x4 t0 = (f32x4){0.f, 0.f, 0.f, 0.f};
            f32x4 t1 = (f32x4){0.f, 0.f, 0.f, 0.f};
            t0 = __builtin_amdgcn_mfma_f32_16x16x32_bf16(a_lo, b0lo, t0, 0, 0, 0);
            t0 = __builtin_amdgcn_mfma_f32_16x16x32_bf16(a_hi, b0hi, t0, 0, 0, 0);
            t1 = __builtin_amdgcn_mfma_f32_16x16x32_bf16(a_lo, b1lo, t1, 0, 0, 0);
            t1 = __builtin_amdgcn_mfma_f32_16x16x32_bf16(a_hi, b1hi, t1, 0, 0, 0);
            S[s][0] = t0; S[s][1] = t1;
        }
        // ---- ensure previous iteration's pbuf reads are drained, then
        //      bias + exp(s-12) + store P (per-wave pbuf; wave-local fence) ----
        LGKM0();
#pragma unroll
        for (int s = 0; s < 2; ++s) {
            int j0 = wv * 384 + s * 192 + c * 32;
            // distance-bucket fast path (wave-uniform branch)
            int lo1 = j0 - (i0 + 15), lo2 = i0 - (j0 + 31);
            int dmin = lo1 > 0 ? lo1 : (lo2 > 0 ? lo2 : 0);
            int dm1 = i0 + 15 - j0, dm2 = j0 + 31 - i0;
            int dmax = dm1 > dm2 ? dm1 : dm2;
            int tlo = 31 - __builtin_clz(dmin + 1);
            int thi = 31 - __builtin_clz(dmax + 1);
            if (tlo == thi) {
#pragma unroll
                for (int r = 0; r < 4; ++r) {
                    int row = quad * 4 + r;
                    float bv = s11b[row * 12 + tlo] - 12.f;
                    float p0 = __expf(S[s][0][r] + bv);
                    float p1 = __expf(S[s][1][r] + bv);
                    pbuf[wv][s][row * 36 + col] = f2b(p0);
                    pbuf[wv][s][row * 36 + 16 + col] = f2b(p1);
                    lsum[r] += p0 + p1;
                }
            } else {
#pragma unroll
                for (int r = 0; r < 4; ++r) {
                    int row = quad * 4 + r;
                    int ig = i0 + row;
                    int d0 = ig - (j0 + col); d0 = d0 < 0 ? -d0 : d0;
                    int d1 = ig - (j0 + 16 + col); d1 = d1 < 0 ? -d1 : d1;
                    float v0 = S[s][0][r] + s11b[row * 12 + (31 - __builtin_clz(d0 + 1))];
                    float v1 = S[s][1][r] + s11b[row * 12 + (31 - __builtin_clz(d1 + 1))];
                    float p0 = __expf(v0 - 12.f);
                    float p1 = __expf(v1 - 12.f);
                    pbuf[wv][s][row * 36 + col] = f2b(p0);
                    pbuf[wv][s][row * 36 + 16 + col] = f2b(p1);
                    lsum[r] += p0 + p1;
                }
            }
        }
        LGKM0();  // pbuf writes visible to this wave's reads
        // ---- PV ----
#pragma unroll
        for (int s = 0; s < 2; ++s) {
            int j0 = wv * 384 + s * 192 + c * 32;
            const u16* pr = &pbuf[wv][s][col * 36 + quad * 8];
            union { s16x8 v; uint2 u2[2]; } pa;
            pa.u2[0] = *(const uint2*)(pr);
            pa.u2[1] = *(const uint2*)(pr + 4);
#pragma unroll
            for (int nt = 0; nt < 6; ++nt) {
                const u16* vr = vt16 + (h * DVH + nt * 16 + col) * NTOK + j0 + quad * 8;
                s16x8 vf = *(const s16x8*)vr;
                O[s][nt] = __builtin_amdgcn_mfma_f32_16x16x32_bf16(pa.v, vf, O[s][nt], 0, 0, 0);
            }
        }
    }

    // ---- per-row l: reduce lsum across the 16 cols (stays within quad) ----
#pragma unroll
    for (int off = 1; off < 16; off <<= 1)
#pragma unroll
        for (int r = 0; r < 4; ++r) lsum[r] += __shfl_xor(lsum[r], off);
    if (col == 0)
#pragma unroll
        for (int r = 0; r < 4; ++r) lw[wv][quad * 4 + r] = lsum[r];
    // ---- stream-sum O -> LDS (no rescale: shared fixed offset) ----
#pragma unroll
    for (int r = 0; r < 4; ++r) {
        int row = quad * 4 + r;
#pragma unroll
        for (int nt = 0; nt < 6; ++nt)
            Om[wv][row * 96 + nt * 16 + col] = O[0][nt][r] + O[1][nt][r];
    }
    __syncthreads();
    // ---- add-merge 4 waves + write ----
    for (int idx = tid; idx < 16 * 96; idx += 256) {
        int row = idx / 96, cc = idx % 96;
        float L = lw[0][row] + lw[1][row] + lw[2][row] + lw[3][row];
        float val = Om[0][idx] + Om[1][idx] + Om[2][idx] + Om[3][idx];
        aob[(i0 + row) * CDIM + h * DVH + cc] = f2b(val / L);
    }
}

// ---------------------------------------------------------------------------
// Kernel 4: output GEMM, register-direct MFMA + bias -> fp32 out.
// ---------------------------------------------------------------------------
__global__ __launch_bounds__(256) void out_reg(const void* __restrict__ bout,
                                               int fb,
                                               float* __restrict__ ws,
                                               float* __restrict__ out) {
    const int* flags = (const int*)ws;
    const u16* aob = (const u16*)(ws + OFF_AOB);
    const u16* wot = (const u16*)(ws + OFF_WOT);
    int f32b = flags[fb];

    int tid = threadIdx.x;
    int lane = tid & 63, w = tid >> 6;
    int quad = lane >> 4, col = lane & 15;
    int i0 = blockIdx.x * 64;
    int n0 = blockIdx.y * 64;

    f32x4 acc[4];
#pragma unroll
    for (int mt = 0; mt < 4; ++mt) acc[mt] = (f32x4){0.f, 0.f, 0.f, 0.f};

    const u16* brow = wot + (n0 + w * 16 + col) * CDIM + quad * 8;
#pragma unroll 2
    for (int k0 = 0; k0 < CDIM; k0 += 64) {
#pragma unroll
        for (int kc = 0; kc < 2; ++kc) {
            s16x8 bfrag = *(const s16x8*)(brow + k0 + kc * 32);
#pragma unroll
            for (int mt = 0; mt < 4; ++mt) {
                s16x8 afrag = *(const s16x8*)(aob + (i0 + mt * 16 + col) * CDIM
                                              + k0 + kc * 32 + quad * 8);
                acc[mt] = __builtin_amdgcn_mfma_f32_16x16x32_bf16(afrag, bfrag, acc[mt], 0, 0, 0);
            }
        }
    }

    int c = n0 + w * 16 + col;
    float bias = ldin(bout, c, f32b);
#pragma unroll
    for (int mt = 0; mt < 4; ++mt) {
#pragma unroll
        for (int r = 0; r < 4; ++r) {
            int i = i0 + mt * 16 + quad * 4 + r;
            out[i * CDIM + c] = acc[mt][r] + bias;
        }
    }
}

// ---------------------------------------------------------------------------
extern "C" void kernel_launch(void* const* d_in, const int* in_sizes, int n_in,
                              void* d_out, int out_size, void* d_ws, size_t ws_size,
                              hipStream_t stream) {
    float* out = (float*)d_out;
    float* ws = (float*)d_ws;

    const int want[9] = {1179648, 393216, 393216, 589824, 589824, 768, 49152, 512, 512};
    int role2in[9], used[9] = {0};
    bool ok = (n_in == 9);
    if (ok) {
        for (int r = 0; r < 9; ++r) {
            int found = -1;
            for (int i = 0; i < 9 && found < 0; ++i)
                if (!used[i] && in_sizes[i] == want[r]) found = i;
            if (found < 0) { ok = false; break; }
            used[found] = 1;
            role2in[r] = found;
        }
    }
    if (!ok) for (int r = 0; r < 9; ++r) role2in[r] = r;

    const void* x    = d_in[role2in[0]];
    const void* Wq   = d_in[role2in[1]];
    const void* Wk   = d_in[role2in[2]];
    const void* Wv   = d_in[role2in[3]];
    const void* Wout = d_in[role2in[4]];
    const void* bout = d_in[role2in[5]];
    const void* Wpos = d_in[role2in[6]];
    const void* rcb  = d_in[role2in[7]];
    const void* rpb  = d_in[role2in[8]];

    In9 s;
    for (int i = 0; i < 9; ++i) { s.p[i] = d_in[i]; s.n[i] = in_sizes[i]; }
    hipLaunchKernelGGL(probe_all, dim3(9), dim3(256), 0, stream, s, (int*)ws);

    hipLaunchKernelGGL(wsuf_k, dim3(11), dim3(512), 0, stream, Wpos, role2in[6], ws);
    hipLaunchKernelGGL(prep_t, dim3(480), dim3(256), 0, stream,
                       Wq, Wk, Wv, Wout,
                       role2in[1], role2in[2], role2in[3], role2in[4], ws);
    hipLaunchKernelGGL(xconv, dim3(1152), dim3(256), 0, stream, x, role2in[0], ws);
    hipLaunchKernelGGL(qkv_reg, dim3(24, 28), dim3(256), 0, stream,
                       rcb, rpb, role2in[7], role2in[8], ws);
    hipLaunchKernelGGL(attn_mfma, dim3(768), dim3(256), 0, stream, ws);
    hipLaunchKernelGGL(out_reg, dim3(24, 12), dim3(256), 0, stream,
                       bout, role2in[5], ws, out);
}

// Round 11
// 186.951 us; speedup vs baseline: 1.2728x; 1.2728x over previous
//
#include <hip/hip_runtime.h>
#include <stdint.h>

#define NTOK 1536
#define CDIM 768
#define NH 8
#define DKH 64
#define DVH 96
#define NF 96

typedef unsigned short u16;
typedef __attribute__((ext_vector_type(8))) short s16x8;   // 8 bf16 (4 VGPRs)
typedef __attribute__((ext_vector_type(4))) float f32x4;   // MFMA acc

#define LGKM0() asm volatile("s_waitcnt lgkmcnt(0)" ::: "memory")

__device__ __forceinline__ float b2f(u16 u) {
    union { uint32_t i; float f; } v; v.i = ((uint32_t)u) << 16; return v.f;
}
__device__ __forceinline__ u16 f2b(float f) {
    union { float f; uint32_t i; } v; v.f = f;
    uint32_t x = v.i;
    return (u16)((x + 0x7FFFu + ((x >> 16) & 1u)) >> 16);
}
__device__ __forceinline__ float ldin(const void* p, int i, int f32) {
    return f32 ? ((const float*)p)[i] : b2f(((const u16*)p)[i]);
}

// Fragment-major layout: within a (16 rows x 32 k) block of 512 bf16,
// element (m, kk) sits at ((kk>>3)*16 + m)*8 + (kk&7)  ==  lane*8 + slot
// for MFMA lane = (kk/8)*16 + m.  One wave-load at base+lane*16B = one frag.
#define FIDX(m, kk) ((((kk) >> 3) * 16 + (m)) * 8 + ((kk) & 7))

// ---------------------------------------------------------------------------
// ws layout (float offsets). flags[0..8] at ws[0..8]. ~14.8 MB.
// All frag buffers: blocks of 512 u16.
// ---------------------------------------------------------------------------
#define OFF_WSUF 16
#define OFF_S11  (OFF_WSUF + 5632)
#define OFF_QF   (OFF_S11 + 147456)     // u16: qfrag  (h,ti:96,kc2:2)  A-frags
#define OFF_KF   (OFF_QF + 393216)      // u16: kfrag  (h,tj:96,kc2:2)  B-frags
#define OFF_VF   (OFF_KF + 393216)      // u16: vfrag  (h,jc:48,nt:6)   B-frags
#define OFF_AOF  (OFF_VF + 589824)      // u16: aofrag (ti:96,kc:24)    A-frags
#define OFF_XF   (OFF_AOF + 589824)     // u16: xfrag  (ti:96,kc:24)    A-frags
#define OFF_WF   (OFF_XF + 589824)      // u16: wfrag  (tn:112,kc:24)   B-frags
#define OFF_WOF  (OFF_WF + 688128)      // u16: wofrag (tn:48,kc:24)    B-frags

struct In9 { const void* p[9]; int n[9]; };

// ---------------------------------------------------------------------------
// Kernel P: per-input dtype probe. flags[k]=1 iff fp32.
// ---------------------------------------------------------------------------
__global__ __launch_bounds__(256) void probe_all(In9 s, int* __restrict__ flags) {
    __shared__ int bad;
    int k = blockIdx.x;
    if (threadIdx.x == 0) bad = 0;
    __syncthreads();
    const u16* a = (const u16*)s.p[k];
    int n = s.n[k];
    if (n > 2048) n = 2048;
    int my = 0;
    for (int i = threadIdx.x; i < n; i += 256) {
        float v = b2f(a[i]);
        if (!(fabsf(v) < 1e6f)) my = 1;
    }
    if (my) atomicOr(&bad, 1);
    __syncthreads();
    if (threadIdx.x == 0) flags[k] = bad;
}

// ---------------------------------------------------------------------------
// Kernel PR: build all fragment-major operand buffers + wsuf.
//   bx [0,96):    xfrag  tile ti  (from x, row-major (i,k))
//   bx [96,208):  wfrag  tile tn  (from Wq|Wk|Wv, (k,n))
//   bx [208,256): wofrag tile tn  (from Wout, (k,n))
//   bx [256,267): wsuf row t
// ---------------------------------------------------------------------------
__global__ __launch_bounds__(256) void prep(const void* __restrict__ x,
                                            const void* __restrict__ Wq,
                                            const void* __restrict__ Wk,
                                            const void* __restrict__ Wv,
                                            const void* __restrict__ Wout,
                                            const void* __restrict__ Wpos,
                                            int fx, int fq, int fk, int fv,
                                            int fw, int fpos,
                                            float* __restrict__ ws) {
    __shared__ float lds[1104];
    const int* flags = (const int*)ws;
    int bx = blockIdx.x, tid = threadIdx.x;

    if (bx >= 256) {  // wsuf
        int t = bx - 256;
        int f = flags[fpos];
        for (int hd = tid; hd < 512; hd += 256) {
            float s = 0.f;
            for (int f0 = t; f0 < NF; ++f0) s += ldin(Wpos, f0 * 512 + hd, f);
            ws[OFF_WSUF + t * 512 + hd] = s;
        }
        return;
    }

    if (bx < 96) {
        // ---- xfrag: tile = 16 rows x 768 k ----
        u16* dst = (u16*)(ws + OFF_XF);
        int ti = bx, f = flags[fx];
        for (int kb = 0; kb < 12; ++kb) {
            for (int idx = tid; idx < 1024; idx += 256) {
                int r = idx >> 6, kk = idx & 63;   // coalesced along k
                lds[r * 68 + kk] = ldin(x, (ti * 16 + r) * CDIM + kb * 64 + kk, f);
            }
            __syncthreads();
            if (tid < 128) {
                int kq = tid >> 4, m = tid & 15;   // kq: 8-k group within 64
                union { u16 u[8]; uint4 v; } pk;
#pragma unroll
                for (int j = 0; j < 8; ++j) pk.u[j] = f2b(lds[m * 68 + kq * 8 + j]);
                int kc = kb * 2 + (kq >> 2);
                *(uint4*)(dst + (ti * 24 + kc) * 512 + ((kq & 3) * 16 + m) * 8) = pk.v;
            }
            __syncthreads();
        }
        return;
    }

    // ---- weight frags: tile = 16 n-cols x 768 k, source (k, n) ----
    u16* dst; int tn; const void* src; int ld, cn0, f;
    if (bx < 208) {
        tn = bx - 96;
        int n0 = tn * 16;
        dst = (u16*)(ws + OFF_WF);
        if (n0 < 512)       { src = Wq; ld = 512;  cn0 = n0;        f = flags[fq]; }
        else if (n0 < 1024) { src = Wk; ld = 512;  cn0 = n0 - 512;  f = flags[fk]; }
        else                { src = Wv; ld = CDIM; cn0 = n0 - 1024; f = flags[fv]; }
    } else {
        tn = bx - 208;
        dst = (u16*)(ws + OFF_WOF);
        src = Wout; ld = CDIM; cn0 = tn * 16; f = flags[fw];
    }
    for (int kb = 0; kb < 12; ++kb) {
        for (int idx = tid; idx < 1024; idx += 256) {
            int kk = idx >> 4, nn = idx & 15;
            lds[kk * 17 + nn] = ldin(src, (kb * 64 + kk) * ld + cn0 + nn, f);
        }
        __syncthreads();
        if (tid < 128) {
            int kq = tid >> 4, nn = tid & 15;
            union { u16 u[8]; uint4 v; } pk;
#pragma unroll
            for (int j = 0; j < 8; ++j) pk.u[j] = f2b(lds[(kq * 8 + j) * 17 + nn]);
            int kc = kb * 2 + (kq >> 2);
            *(uint4*)(dst + (tn * 24 + kc) * 512 + ((kq & 3) * 16 + nn) * 8) = pk.v;
        }
        __syncthreads();
    }
}

// ---------------------------------------------------------------------------
// Kernel 1: QKV GEMM, register-direct MFMA with fragment-major operands.
// Grid (24, 28): 64 rows x 64 n-cols per block; wave w owns n-tile tn4*4+w.
// Inner loop: contiguous 1KB wave-loads only.  Fused s11+qfrag epilogue for Q.
// ---------------------------------------------------------------------------
__global__ __launch_bounds__(256) void qkv_reg(const void* __restrict__ rcb,
                                               const void* __restrict__ rpb,
                                               int fc, int fp,
                                               float* __restrict__ ws) {
    __shared__ float qt[64 * 68];
    __shared__ float rpd[12];
    const int* flags = (const int*)ws;
    const u16* xf = (const u16*)(ws + OFF_XF);
    const u16* wf = (const u16*)(ws + OFF_WF);
    u16* qf = (u16*)(ws + OFF_QF);
    u16* kf = (u16*)(ws + OFF_KF);
    u16* vf = (u16*)(ws + OFF_VF);

    int tid = threadIdx.x;
    int lane = tid & 63, w = tid >> 6;
    int quad = lane >> 4, col = lane & 15;
    int ti4 = blockIdx.x;         // 4 i-tiles (64 rows)
    int tn4 = blockIdx.y;         // 4 n-tiles (64 cols); wave w -> tn
    int tn = tn4 * 4 + w;
    int i0 = ti4 * 64;
    bool isQ = (tn4 < 8);
    int hq = tn4;                 // Q blocks cover exactly one head

    if (isQ && tid < 12) {
        float s = 0.f;
        if (tid < 11) {
            const float* wp = ws + OFF_WSUF + tid * 512 + hq * 64;
            int f32p = flags[fp];
            for (int d = 0; d < 64; ++d) s += ldin(rpb, hq * 64 + d, f32p) * wp[d];
        }
        rpd[tid] = s;
    }

    f32x4 acc[4];
#pragma unroll
    for (int mt = 0; mt < 4; ++mt) acc[mt] = (f32x4){0.f, 0.f, 0.f, 0.f};

    const u16* bp = wf + (tn * 24) * 512 + lane * 8;
    const u16* ap = xf + (ti4 * 4 * 24) * 512 + lane * 8;
#pragma unroll 4
    for (int kc = 0; kc < 24; ++kc) {
        s16x8 bfrag = *(const s16x8*)(bp + kc * 512);
#pragma unroll
        for (int mt = 0; mt < 4; ++mt) {
            s16x8 afrag = *(const s16x8*)(ap + (mt * 24 + kc) * 512);
            acc[mt] = __builtin_amdgcn_mfma_f32_16x16x32_bf16(afrag, bfrag, acc[mt], 0, 0, 0);
        }
    }

    if (isQ) {
#pragma unroll
        for (int mt = 0; mt < 4; ++mt)
#pragma unroll
            for (int r = 0; r < 4; ++r)
                qt[(mt * 16 + quad * 4 + r) * 68 + w * 16 + col] = acc[mt][r] * 0.125f;
        __syncthreads();
        int f32c = flags[fc];
        for (int idx = tid; idx < 64 * 64; idx += 256) {
            int row = idx >> 6, d = idx & 63;
            int ti = ti4 * 4 + (row >> 4), m = row & 15;
            u16 val = f2b(qt[row * 68 + d] + ldin(rcb, hq * 64 + d, f32c));
            qf[((hq * 96 + ti) * 2 + (d >> 5)) * 512 + FIDX(m, d & 31)] = val;
        }
        const float* wsuf = ws + OFF_WSUF;
        float* s11 = ws + OFF_S11;
        for (int idx = tid; idx < 64 * 12; idx += 256) {
            int row = idx / 12, t = idx % 12;
            float s = rpd[t];
            if (t < 11) {
                const float* wp = wsuf + t * 512 + hq * 64;
                const float* qr = qt + row * 68;
                for (int d = 0; d < 64; ++d) s += qr[d] * wp[d];
            }
            s11[(hq * NTOK + i0 + row) * 12 + t] = s;
        }
    } else if (tn < 64) {
        // K: tn in [32,64): head h, dims dcol0..+16; write kfrag B-layout
        int h = (tn >> 2) - 8;
        int d = ((tn & 3) * 16) + col;
#pragma unroll
        for (int mt = 0; mt < 4; ++mt) {
            int tj = ti4 * 4 + mt;
#pragma unroll
            for (int r = 0; r < 4; ++r) {
                int nn = quad * 4 + r;  // j within tile
                kf[((h * 96 + tj) * 2 + (d >> 5)) * 512 + FIDX(nn, d & 31)] = f2b(acc[mt][r]);
            }
        }
    } else {
        // V: write vfrag B-layout (K-dim = key j, N-dim = v-dim d)
        int c = tn * 16 + col - 1024;
        int h = c / 96, d = c % 96;
        int nt = d >> 4, nn = d & 15;
#pragma unroll
        for (int mt = 0; mt < 4; ++mt) {
#pragma unroll
            for (int r = 0; r < 4; ++r) {
                int j = i0 + mt * 16 + quad * 4 + r;
                int jc = j >> 5, kk = j & 31;
                vf[((h * 48 + jc) * 6 + nt) * 512 + FIDX(nn, kk)] = f2b(acc[mt][r]);
            }
        }
    }
}

// ---------------------------------------------------------------------------
// Kernel 3: MFMA flash attention, fixed-offset softmax, fragment-major loads.
// Grid 768 = 8 heads x 96 Q-tiles(16 rows); 4 waves split keys 384 each
// (2 streams x 6 chunks x 32 keys).  Per-wave pbuf with lgkmcnt fences.
// ---------------------------------------------------------------------------
__global__ __launch_bounds__(256) void attn_mfma(float* __restrict__ ws) {
    __shared__ float s11b[192];
    __shared__ alignas(16) u16 pbuf[4][2][16 * 36];
    __shared__ float Om[4][16 * 96];
    __shared__ float lw[4][16];

    const u16* qf = (const u16*)(ws + OFF_QF);
    const u16* kf = (const u16*)(ws + OFF_KF);
    const u16* vf = (const u16*)(ws + OFF_VF);
    const float* s11 = ws + OFF_S11;
    u16* aof = (u16*)(ws + OFF_AOF);

    int h = blockIdx.x & 7;               // XCD-affine
    int ti = blockIdx.x >> 3;
    int i0 = ti * 16;
    int tid = threadIdx.x;
    int wv = tid >> 6, lane = tid & 63;
    int quad = lane >> 4, col = lane & 15;

    if (tid < 192) s11b[tid] = s11[(h * NTOK + i0 + tid / 12) * 12 + tid % 12];
    const u16* qp = qf + ((h * 96 + ti) * 2) * 512 + lane * 8;
    s16x8 a_lo = *(const s16x8*)(qp);
    s16x8 a_hi = *(const s16x8*)(qp + 512);
    __syncthreads();

    f32x4 O[2][6];
    float lsum[4];
#pragma unroll
    for (int s = 0; s < 2; ++s)
#pragma unroll
        for (int nt = 0; nt < 6; ++nt) O[s][nt] = (f32x4){0.f, 0.f, 0.f, 0.f};
#pragma unroll
    for (int r = 0; r < 4; ++r) lsum[r] = 0.f;

    for (int c = 0; c < 6; ++c) {
        f32x4 S[2][2];
        // ---- QK^T: frag loads are contiguous 1KB ----
#pragma unroll
        for (int s = 0; s < 2; ++s) {
            int tj0 = wv * 24 + s * 12 + c * 2;
            const u16* kp = kf + ((h * 96 + tj0) * 2) * 512 + lane * 8;
            s16x8 b0lo = *(const s16x8*)(kp);
            s16x8 b0hi = *(const s16x8*)(kp + 512);
            s16x8 b1lo = *(const s16x8*)(kp + 1024);
            s16x8 b1hi = *(const s16x8*)(kp + 1536);
            f32x4 t0 = (f32x4){0.f, 0.f, 0.f, 0.f};
            f32x4 t1 = (f32x4){0.f, 0.f, 0.f, 0.f};
            t0 = __builtin_amdgcn_mfma_f32_16x16x32_bf16(a_lo, b0lo, t0, 0, 0, 0);
            t0 = __builtin_amdgcn_mfma_f32_16x16x32_bf16(a_hi, b0hi, t0, 0, 0, 0);
            t1 = __builtin_amdgcn_mfma_f32_16x16x32_bf16(a_lo, b1lo, t1, 0, 0, 0);
            t1 = __builtin_amdgcn_mfma_f32_16x16x32_bf16(a_hi, b1hi, t1, 0, 0, 0);
            S[s][0] = t0; S[s][1] = t1;
        }
        LGKM0();  // drain previous iter's pbuf reads before overwrite
#pragma unroll
        for (int s = 0; s < 2; ++s) {
            int j0 = wv * 384 + s * 192 + c * 32;
            int lo1 = j0 - (i0 + 15), lo2 = i0 - (j0 + 31);
            int dmin = lo1 > 0 ? lo1 : (lo2 > 0 ? lo2 : 0);
            int dm1 = i0 + 15 - j0, dm2 = j0 + 31 - i0;
            int dmax = dm1 > dm2 ? dm1 : dm2;
            int tlo = 31 - __builtin_clz(dmin + 1);
            int thi = 31 - __builtin_clz(dmax + 1);
            if (tlo == thi) {
#pragma unroll
                for (int r = 0; r < 4; ++r) {
                    int row = quad * 4 + r;
                    float bv = s11b[row * 12 + tlo] - 12.f;
                    float p0 = __expf(S[s][0][r] + bv);
                    float p1 = __expf(S[s][1][r] + bv);
                    pbuf[wv][s][row * 36 + col] = f2b(p0);
                    pbuf[wv][s][row * 36 + 16 + col] = f2b(p1);
                    lsum[r] += p0 + p1;
                }
            } else {
#pragma unroll
                for (int r = 0; r < 4; ++r) {
                    int row = quad * 4 + r;
                    int ig = i0 + row;
                    int d0 = ig - (j0 + col); d0 = d0 < 0 ? -d0 : d0;
                    int d1 = ig - (j0 + 16 + col); d1 = d1 < 0 ? -d1 : d1;
                    float v0 = S[s][0][r] + s11b[row * 12 + (31 - __builtin_clz(d0 + 1))];
                    float v1 = S[s][1][r] + s11b[row * 12 + (31 - __builtin_clz(d1 + 1))];
                    float p0 = __expf(v0 - 12.f);
                    float p1 = __expf(v1 - 12.f);
                    pbuf[wv][s][row * 36 + col] = f2b(p0);
                    pbuf[wv][s][row * 36 + 16 + col] = f2b(p1);
                    lsum[r] += p0 + p1;
                }
            }
        }
        LGKM0();  // pbuf writes visible to this wave
        // ---- PV: frag loads contiguous ----
#pragma unroll
        for (int s = 0; s < 2; ++s) {
            int jc = wv * 12 + s * 6 + c;
            const u16* pr = &pbuf[wv][s][col * 36 + quad * 8];
            union { s16x8 v; uint2 u2[2]; } pa;
            pa.u2[0] = *(const uint2*)(pr);
            pa.u2[1] = *(const uint2*)(pr + 4);
            const u16* vp = vf + ((h * 48 + jc) * 6) * 512 + lane * 8;
#pragma unroll
            for (int nt = 0; nt < 6; ++nt) {
                s16x8 vfr = *(const s16x8*)(vp + nt * 512);
                O[s][nt] = __builtin_amdgcn_mfma_f32_16x16x32_bf16(pa.v, vfr, O[s][nt], 0, 0, 0);
            }
        }
    }

#pragma unroll
    for (int off = 1; off < 16; off <<= 1)
#pragma unroll
        for (int r = 0; r < 4; ++r) lsum[r] += __shfl_xor(lsum[r], off);
    if (col == 0)
#pragma unroll
        for (int r = 0; r < 4; ++r) lw[wv][quad * 4 + r] = lsum[r];
#pragma unroll
    for (int r = 0; r < 4; ++r) {
        int row = quad * 4 + r;
#pragma unroll
        for (int nt = 0; nt < 6; ++nt)
            Om[wv][row * 96 + nt * 16 + col] = O[0][nt][r] + O[1][nt][r];
    }
    __syncthreads();
    // ---- add-merge 4 waves; write aofrag (A-layout for out GEMM) ----
    for (int idx = tid; idx < 16 * 96; idx += 256) {
        int row = idx / 96, cc = idx % 96;
        float L = lw[0][row] + lw[1][row] + lw[2][row] + lw[3][row];
        float val = (Om[0][idx] + Om[1][idx] + Om[2][idx] + Om[3][idx]) / L;
        aof[(ti * 24 + h * 3 + (cc >> 5)) * 512 + FIDX(row, cc & 31)] = f2b(val);
    }
}

// ---------------------------------------------------------------------------
// Kernel 4: output GEMM, register-direct MFMA, fragment-major + bias -> fp32.
// Grid (24, 12).
// ---------------------------------------------------------------------------
__global__ __launch_bounds__(256) void out_reg(const void* __restrict__ bout,
                                               int fb,
                                               float* __restrict__ ws,
                                               float* __restrict__ out) {
    const int* flags = (const int*)ws;
    const u16* af = (const u16*)(ws + OFF_AOF);
    const u16* wof = (const u16*)(ws + OFF_WOF);
    int f32b = flags[fb];

    int tid = threadIdx.x;
    int lane = tid & 63, w = tid >> 6;
    int quad = lane >> 4, col = lane & 15;
    int ti4 = blockIdx.x;
    int tn = blockIdx.y * 4 + w;
    int i0 = ti4 * 64;
    int n0 = blockIdx.y * 64;

    f32x4 acc[4];
#pragma unroll
    for (int mt = 0; mt < 4; ++mt) acc[mt] = (f32x4){0.f, 0.f, 0.f, 0.f};

    const u16* bp = wof + (tn * 24) * 512 + lane * 8;
    const u16* ap = af + (ti4 * 4 * 24) * 512 + lane * 8;
#pragma unroll 4
    for (int kc = 0; kc < 24; ++kc) {
        s16x8 bfrag = *(const s16x8*)(bp + kc * 512);
#pragma unroll
        for (int mt = 0; mt < 4; ++mt) {
            s16x8 afrag = *(const s16x8*)(ap + (mt * 24 + kc) * 512);
            acc[mt] = __builtin_amdgcn_mfma_f32_16x16x32_bf16(afrag, bfrag, acc[mt], 0, 0, 0);
        }
    }

    int c = n0 + w * 16 + col;
    float bias = ldin(bout, c, f32b);
#pragma unroll
    for (int mt = 0; mt < 4; ++mt) {
#pragma unroll
        for (int r = 0; r < 4; ++r) {
            int i = i0 + mt * 16 + quad * 4 + r;
            out[i * CDIM + c] = acc[mt][r] + bias;
        }
    }
}

// ---------------------------------------------------------------------------
extern "C" void kernel_launch(void* const* d_in, const int* in_sizes, int n_in,
                              void* d_out, int out_size, void* d_ws, size_t ws_size,
                              hipStream_t stream) {
    float* out = (float*)d_out;
    float* ws = (float*)d_ws;

    const int want[9] = {1179648, 393216, 393216, 589824, 589824, 768, 49152, 512, 512};
    int role2in[9], used[9] = {0};
    bool ok = (n_in == 9);
    if (ok) {
        for (int r = 0; r < 9; ++r) {
            int found = -1;
            for (int i = 0; i < 9 && found < 0; ++i)
                if (!used[i] && in_sizes[i] == want[r]) found = i;
            if (found < 0) { ok = false; break; }
            used[found] = 1;
            role2in[r] = found;
        }
    }
    if (!ok) for (int r = 0; r < 9; ++r) role2in[r] = r;

    const void* x    = d_in[role2in[0]];
    const void* Wq   = d_in[role2in[1]];
    const void* Wk   = d_in[role2in[2]];
    const void* Wv   = d_in[role2in[3]];
    const void* Wout = d_in[role2in[4]];
    const void* bout = d_in[role2in[5]];
    const void* Wpos = d_in[role2in[6]];
    const void* rcb  = d_in[role2in[7]];
    const void* rpb  = d_in[role2in[8]];

    In9 s;
    for (int i = 0; i < 9; ++i) { s.p[i] = d_in[i]; s.n[i] = in_sizes[i]; }
    hipLaunchKernelGGL(probe_all, dim3(9), dim3(256), 0, stream, s, (int*)ws);

    hipLaunchKernelGGL(prep, dim3(267), dim3(256), 0, stream,
                       x, Wq, Wk, Wv, Wout, Wpos,
                       role2in[0], role2in[1], role2in[2], role2in[3],
                       role2in[4], role2in[6], ws);
    hipLaunchKernelGGL(qkv_reg, dim3(24, 28), dim3(256), 0, stream,
                       rcb, rpb, role2in[7], role2in[8], ws);
    hipLaunchKernelGGL(attn_mfma, dim3(768), dim3(256), 0, stream, ws);
    hipLaunchKernelGGL(out_reg, dim3(24, 12), dim3(256), 0, stream,
                       bout, role2in[5], ws, out);
}

// Round 12
// 185.279 us; speedup vs baseline: 1.2843x; 1.0090x over previous
//
#include <hip/hip_runtime.h>
#include <stdint.h>

#define NTOK 1536
#define CDIM 768
#define NH 8
#define DKH 64
#define DVH 96
#define NF 96

typedef unsigned short u16;
typedef __attribute__((ext_vector_type(8))) short s16x8;   // 8 bf16 (4 VGPRs)
typedef __attribute__((ext_vector_type(4))) float f32x4;   // MFMA acc

#define LGKM0() asm volatile("s_waitcnt lgkmcnt(0)" ::: "memory")

__device__ __forceinline__ float b2f(u16 u) {
    union { uint32_t i; float f; } v; v.i = ((uint32_t)u) << 16; return v.f;
}
__device__ __forceinline__ u16 f2b(float f) {
    union { float f; uint32_t i; } v; v.f = f;
    uint32_t x = v.i;
    return (u16)((x + 0x7FFFu + ((x >> 16) & 1u)) >> 16);
}
__device__ __forceinline__ float ldin(const void* p, int i, int f32) {
    return f32 ? ((const float*)p)[i] : b2f(((const u16*)p)[i]);
}

// Fragment-major layout: within a (16 rows x 32 k) block of 512 bf16,
// element (m, kk) sits at ((kk>>3)*16 + m)*8 + (kk&7)  ==  lane*8 + slot
// for MFMA lane = (kk/8)*16 + m.  One wave-load at base+lane*16B = one frag.
#define FIDX(m, kk) ((((kk) >> 3) * 16 + (m)) * 8 + ((kk) & 7))

// ---------------------------------------------------------------------------
// ws layout (float offsets). flags[0..8] at ws[0..8]. ~14.8 MB.
// ---------------------------------------------------------------------------
#define OFF_WSUF 16
#define OFF_S11  (OFF_WSUF + 5632)
#define OFF_QF   (OFF_S11 + 147456)     // u16: qfrag  (h,ti:96,kc2:2)  A-frags
#define OFF_KF   (OFF_QF + 393216)      // u16: kfrag  (h,tj:96,kc2:2)  B-frags
#define OFF_VF   (OFF_KF + 393216)      // u16: vfrag  (h,jc:48,nt:6)   B-frags
#define OFF_AOF  (OFF_VF + 589824)      // u16: aofrag (ti:96,kc:24)    A-frags
#define OFF_XF   (OFF_AOF + 589824)     // u16: xfrag  (ti:96,kc:24)    A-frags
#define OFF_WF   (OFF_XF + 589824)      // u16: wfrag  (tn:112,kc:24)   B-frags
#define OFF_WOF  (OFF_WF + 688128)      // u16: wofrag (tn:48,kc:24)    B-frags

struct In9 { const void* p[9]; int n[9]; };

// ---------------------------------------------------------------------------
// Kernel P: per-input dtype probe. flags[k]=1 iff fp32.
// ---------------------------------------------------------------------------
__global__ __launch_bounds__(256) void probe_all(In9 s, int* __restrict__ flags) {
    __shared__ int bad;
    int k = blockIdx.x;
    if (threadIdx.x == 0) bad = 0;
    __syncthreads();
    const u16* a = (const u16*)s.p[k];
    int n = s.n[k];
    if (n > 2048) n = 2048;
    int my = 0;
    for (int i = threadIdx.x; i < n; i += 256) {
        float v = b2f(a[i]);
        if (!(fabsf(v) < 1e6f)) my = 1;
    }
    if (my) atomicOr(&bad, 1);
    __syncthreads();
    if (threadIdx.x == 0) flags[k] = bad;
}

// ---------------------------------------------------------------------------
// Kernel PR: build fragment buffers, flat grid (latency-parallel):
//   bx [0,576):      xfrag — 4 chunks/block (1 per wave), NO LDS/barrier:
//                    frag lanes read 8 k-contiguous source elems directly.
//   bx [576,1920):   wfrag tile (tn,kb) — 1 load + 1 barrier + pack.
//   bx [1920,2496):  wofrag tile.
//   bx [2496,2507):  wsuf row t.
// ---------------------------------------------------------------------------
__global__ __launch_bounds__(256) void prep(const void* __restrict__ x,
                                            const void* __restrict__ Wq,
                                            const void* __restrict__ Wk,
                                            const void* __restrict__ Wv,
                                            const void* __restrict__ Wout,
                                            const void* __restrict__ Wpos,
                                            int fx, int fq, int fk, int fv,
                                            int fw, int fpos,
                                            float* __restrict__ ws) {
    __shared__ float lds[64 * 17];
    const int* flags = (const int*)ws;
    int bx = blockIdx.x, tid = threadIdx.x;

    if (bx < 576) {
        // ---- xfrag: direct register path, no LDS ----
        int f = flags[fx];
        u16* dst = (u16*)(ws + OFF_XF);
        int wv = tid >> 6, L = tid & 63;
        int idx = bx * 4 + wv;            // chunk in [0, 2304): (ti, kc)
        int ti = idx / 24, kc = idx % 24;
        int m = L & 15, kq = L >> 4;
        int src = (ti * 16 + m) * CDIM + kc * 32 + kq * 8;
        union { u16 u[8]; uint4 v; } pk;
        if (f) {
            const float* xp = (const float*)x + src;
            float4 a = *(const float4*)(xp);
            float4 b = *(const float4*)(xp + 4);
            pk.u[0] = f2b(a.x); pk.u[1] = f2b(a.y); pk.u[2] = f2b(a.z); pk.u[3] = f2b(a.w);
            pk.u[4] = f2b(b.x); pk.u[5] = f2b(b.y); pk.u[6] = f2b(b.z); pk.u[7] = f2b(b.w);
        } else {
            pk.v = *(const uint4*)((const u16*)x + src);
        }
        *(uint4*)(dst + idx * 512 + L * 8) = pk.v;
        return;
    }
    int b2 = bx - 576;
    if (b2 >= 1920) {
        // ---- wsuf ----
        int t = b2 - 1920;
        int f = flags[fpos];
        for (int hd = tid; hd < 512; hd += 256) {
            float s = 0.f;
            for (int f0 = t; f0 < NF; ++f0) s += ldin(Wpos, f0 * 512 + hd, f);
            ws[OFF_WSUF + t * 512 + hd] = s;
        }
        return;
    }
    // ---- weight tile (tn, kb): 64 k x 16 n ----
    const void* src; int ld, cn0, f; u16* dst; int tn, kb;
    if (b2 < 1344) {
        tn = b2 / 12; kb = b2 % 12;
        int n0 = tn * 16;
        dst = (u16*)(ws + OFF_WF);
        if (n0 < 512)       { src = Wq; ld = 512;  cn0 = n0;        f = flags[fq]; }
        else if (n0 < 1024) { src = Wk; ld = 512;  cn0 = n0 - 512;  f = flags[fk]; }
        else                { src = Wv; ld = CDIM; cn0 = n0 - 1024; f = flags[fv]; }
    } else {
        int b3 = b2 - 1344;
        tn = b3 / 12; kb = b3 % 12;
        dst = (u16*)(ws + OFF_WOF);
        src = Wout; ld = CDIM; cn0 = tn * 16; f = flags[fw];
    }
#pragma unroll
    for (int it = 0; it < 4; ++it) {
        int idx = it * 256 + tid;
        int kk = idx >> 4, nn = idx & 15;
        lds[kk * 17 + nn] = ldin(src, (kb * 64 + kk) * ld + cn0 + nn, f);
    }
    __syncthreads();
    if (tid < 128) {
        int half = tid >> 6, L = tid & 63;
        int nn = L & 15, kq = L >> 4;
        union { u16 u[8]; uint4 v; } pk;
#pragma unroll
        for (int j = 0; j < 8; ++j) pk.u[j] = f2b(lds[(half * 32 + kq * 8 + j) * 17 + nn]);
        *(uint4*)(dst + (tn * 24 + kb * 2 + half) * 512 + L * 8) = pk.v;
    }
}

// ---------------------------------------------------------------------------
// Kernel 1: QKV GEMM, register-direct MFMA with fragment-major operands.
// ---------------------------------------------------------------------------
__global__ __launch_bounds__(256) void qkv_reg(const void* __restrict__ rcb,
                                               const void* __restrict__ rpb,
                                               int fc, int fp,
                                               float* __restrict__ ws) {
    __shared__ float qt[64 * 68];
    __shared__ float rpd[12];
    const int* flags = (const int*)ws;
    const u16* xf = (const u16*)(ws + OFF_XF);
    const u16* wf = (const u16*)(ws + OFF_WF);
    u16* qf = (u16*)(ws + OFF_QF);
    u16* kf = (u16*)(ws + OFF_KF);
    u16* vf = (u16*)(ws + OFF_VF);

    int tid = threadIdx.x;
    int lane = tid & 63, w = tid >> 6;
    int quad = lane >> 4, col = lane & 15;
    int ti4 = blockIdx.x;
    int tn4 = blockIdx.y;
    int tn = tn4 * 4 + w;
    int i0 = ti4 * 64;
    bool isQ = (tn4 < 8);
    int hq = tn4;

    if (isQ && tid < 12) {
        float s = 0.f;
        if (tid < 11) {
            const float* wp = ws + OFF_WSUF + tid * 512 + hq * 64;
            int f32p = flags[fp];
            for (int d = 0; d < 64; ++d) s += ldin(rpb, hq * 64 + d, f32p) * wp[d];
        }
        rpd[tid] = s;
    }

    f32x4 acc[4];
#pragma unroll
    for (int mt = 0; mt < 4; ++mt) acc[mt] = (f32x4){0.f, 0.f, 0.f, 0.f};

    const u16* bp = wf + (tn * 24) * 512 + lane * 8;
    const u16* ap = xf + (ti4 * 4 * 24) * 512 + lane * 8;
#pragma unroll 4
    for (int kc = 0; kc < 24; ++kc) {
        s16x8 bfrag = *(const s16x8*)(bp + kc * 512);
#pragma unroll
        for (int mt = 0; mt < 4; ++mt) {
            s16x8 afrag = *(const s16x8*)(ap + (mt * 24 + kc) * 512);
            acc[mt] = __builtin_amdgcn_mfma_f32_16x16x32_bf16(afrag, bfrag, acc[mt], 0, 0, 0);
        }
    }

    if (isQ) {
#pragma unroll
        for (int mt = 0; mt < 4; ++mt)
#pragma unroll
            for (int r = 0; r < 4; ++r)
                qt[(mt * 16 + quad * 4 + r) * 68 + w * 16 + col] = acc[mt][r] * 0.125f;
        __syncthreads();
        int f32c = flags[fc];
        for (int idx = tid; idx < 64 * 64; idx += 256) {
            int row = idx >> 6, d = idx & 63;
            int ti = ti4 * 4 + (row >> 4), m = row & 15;
            u16 val = f2b(qt[row * 68 + d] + ldin(rcb, hq * 64 + d, f32c));
            qf[((hq * 96 + ti) * 2 + (d >> 5)) * 512 + FIDX(m, d & 31)] = val;
        }
        const float* wsuf = ws + OFF_WSUF;
        float* s11 = ws + OFF_S11;
        for (int idx = tid; idx < 64 * 12; idx += 256) {
            int row = idx / 12, t = idx % 12;
            float s = rpd[t];
            if (t < 11) {
                const float* wp = wsuf + t * 512 + hq * 64;
                const float* qr = qt + row * 68;
                for (int d = 0; d < 64; ++d) s += qr[d] * wp[d];
            }
            s11[(hq * NTOK + i0 + row) * 12 + t] = s;
        }
    } else if (tn < 64) {
        int h = (tn >> 2) - 8;
        int d = ((tn & 3) * 16) + col;
#pragma unroll
        for (int mt = 0; mt < 4; ++mt) {
            int tj = ti4 * 4 + mt;
#pragma unroll
            for (int r = 0; r < 4; ++r) {
                int nn = quad * 4 + r;
                kf[((h * 96 + tj) * 2 + (d >> 5)) * 512 + FIDX(nn, d & 31)] = f2b(acc[mt][r]);
            }
        }
    } else {
        int c = tn * 16 + col - 1024;
        int h = c / 96, d = c % 96;
        int nt = d >> 4, nn = d & 15;
#pragma unroll
        for (int mt = 0; mt < 4; ++mt) {
#pragma unroll
            for (int r = 0; r < 4; ++r) {
                int j = i0 + mt * 16 + quad * 4 + r;
                int jc = j >> 5, kk = j & 31;
                vf[((h * 48 + jc) * 6 + nt) * 512 + FIDX(nn, kk)] = f2b(acc[mt][r]);
            }
        }
    }
}

// ---------------------------------------------------------------------------
// Kernel 3: MFMA flash attention, fixed-offset softmax, fragment-major loads.
// ---------------------------------------------------------------------------
__global__ __launch_bounds__(256) void attn_mfma(float* __restrict__ ws) {
    __shared__ float s11b[192];
    __shared__ alignas(16) u16 pbuf[4][2][16 * 36];
    __shared__ float Om[4][16 * 96];
    __shared__ float lw[4][16];

    const u16* qf = (const u16*)(ws + OFF_QF);
    const u16* kf = (const u16*)(ws + OFF_KF);
    const u16* vf = (const u16*)(ws + OFF_VF);
    const float* s11 = ws + OFF_S11;
    u16* aof = (u16*)(ws + OFF_AOF);

    int h = blockIdx.x & 7;
    int ti = blockIdx.x >> 3;
    int i0 = ti * 16;
    int tid = threadIdx.x;
    int wv = tid >> 6, lane = tid & 63;
    int quad = lane >> 4, col = lane & 15;

    if (tid < 192) s11b[tid] = s11[(h * NTOK + i0 + tid / 12) * 12 + tid % 12];
    const u16* qp = qf + ((h * 96 + ti) * 2) * 512 + lane * 8;
    s16x8 a_lo = *(const s16x8*)(qp);
    s16x8 a_hi = *(const s16x8*)(qp + 512);
    __syncthreads();

    f32x4 O[2][6];
    float lsum[4];
#pragma unroll
    for (int s = 0; s < 2; ++s)
#pragma unroll
        for (int nt = 0; nt < 6; ++nt) O[s][nt] = (f32x4){0.f, 0.f, 0.f, 0.f};
#pragma unroll
    for (int r = 0; r < 4; ++r) lsum[r] = 0.f;

    for (int c = 0; c < 6; ++c) {
        f32x4 S[2][2];
#pragma unroll
        for (int s = 0; s < 2; ++s) {
            int tj0 = wv * 24 + s * 12 + c * 2;
            const u16* kp = kf + ((h * 96 + tj0) * 2) * 512 + lane * 8;
            s16x8 b0lo = *(const s16x8*)(kp);
            s16x8 b0hi = *(const s16x8*)(kp + 512);
            s16x8 b1lo = *(const s16x8*)(kp + 1024);
            s16x8 b1hi = *(const s16x8*)(kp + 1536);
            f32x4 t0 = (f32x4){0.f, 0.f, 0.f, 0.f};
            f32x4 t1 = (f32x4){0.f, 0.f, 0.f, 0.f};
            t0 = __builtin_amdgcn_mfma_f32_16x16x32_bf16(a_lo, b0lo, t0, 0, 0, 0);
            t0 = __builtin_amdgcn_mfma_f32_16x16x32_bf16(a_hi, b0hi, t0, 0, 0, 0);
            t1 = __builtin_amdgcn_mfma_f32_16x16x32_bf16(a_lo, b1lo, t1, 0, 0, 0);
            t1 = __builtin_amdgcn_mfma_f32_16x16x32_bf16(a_hi, b1hi, t1, 0, 0, 0);
            S[s][0] = t0; S[s][1] = t1;
        }
        LGKM0();
#pragma unroll
        for (int s = 0; s < 2; ++s) {
            int j0 = wv * 384 + s * 192 + c * 32;
            int lo1 = j0 - (i0 + 15), lo2 = i0 - (j0 + 31);
            int dmin = lo1 > 0 ? lo1 : (lo2 > 0 ? lo2 : 0);
            int dm1 = i0 + 15 - j0, dm2 = j0 + 31 - i0;
            int dmax = dm1 > dm2 ? dm1 : dm2;
            int tlo = 31 - __builtin_clz(dmin + 1);
            int thi = 31 - __builtin_clz(dmax + 1);
            if (tlo == thi) {
#pragma unroll
                for (int r = 0; r < 4; ++r) {
                    int row = quad * 4 + r;
                    float bv = s11b[row * 12 + tlo] - 12.f;
                    float p0 = __expf(S[s][0][r] + bv);
                    float p1 = __expf(S[s][1][r] + bv);
                    pbuf[wv][s][row * 36 + col] = f2b(p0);
                    pbuf[wv][s][row * 36 + 16 + col] = f2b(p1);
                    lsum[r] += p0 + p1;
                }
            } else {
#pragma unroll
                for (int r = 0; r < 4; ++r) {
                    int row = quad * 4 + r;
                    int ig = i0 + row;
                    int d0 = ig - (j0 + col); d0 = d0 < 0 ? -d0 : d0;
                    int d1 = ig - (j0 + 16 + col); d1 = d1 < 0 ? -d1 : d1;
                    float v0 = S[s][0][r] + s11b[row * 12 + (31 - __builtin_clz(d0 + 1))];
                    float v1 = S[s][1][r] + s11b[row * 12 + (31 - __builtin_clz(d1 + 1))];
                    float p0 = __expf(v0 - 12.f);
                    float p1 = __expf(v1 - 12.f);
                    pbuf[wv][s][row * 36 + col] = f2b(p0);
                    pbuf[wv][s][row * 36 + 16 + col] = f2b(p1);
                    lsum[r] += p0 + p1;
                }
            }
        }
        LGKM0();
#pragma unroll
        for (int s = 0; s < 2; ++s) {
            int jc = wv * 12 + s * 6 + c;
            const u16* pr = &pbuf[wv][s][col * 36 + quad * 8];
            union { s16x8 v; uint2 u2[2]; } pa;
            pa.u2[0] = *(const uint2*)(pr);
            pa.u2[1] = *(const uint2*)(pr + 4);
            const u16* vp = vf + ((h * 48 + jc) * 6) * 512 + lane * 8;
#pragma unroll
            for (int nt = 0; nt < 6; ++nt) {
                s16x8 vfr = *(const s16x8*)(vp + nt * 512);
                O[s][nt] = __builtin_amdgcn_mfma_f32_16x16x32_bf16(pa.v, vfr, O[s][nt], 0, 0, 0);
            }
        }
    }

#pragma unroll
    for (int off = 1; off < 16; off <<= 1)
#pragma unroll
        for (int r = 0; r < 4; ++r) lsum[r] += __shfl_xor(lsum[r], off);
    if (col == 0)
#pragma unroll
        for (int r = 0; r < 4; ++r) lw[wv][quad * 4 + r] = lsum[r];
#pragma unroll
    for (int r = 0; r < 4; ++r) {
        int row = quad * 4 + r;
#pragma unroll
        for (int nt = 0; nt < 6; ++nt)
            Om[wv][row * 96 + nt * 16 + col] = O[0][nt][r] + O[1][nt][r];
    }
    __syncthreads();
    for (int idx = tid; idx < 16 * 96; idx += 256) {
        int row = idx / 96, cc = idx % 96;
        float L = lw[0][row] + lw[1][row] + lw[2][row] + lw[3][row];
        float val = (Om[0][idx] + Om[1][idx] + Om[2][idx] + Om[3][idx]) / L;
        aof[(ti * 24 + h * 3 + (cc >> 5)) * 512 + FIDX(row, cc & 31)] = f2b(val);
    }
}

// ---------------------------------------------------------------------------
// Kernel 4: output GEMM, register-direct MFMA, fragment-major + bias -> fp32.
// ---------------------------------------------------------------------------
__global__ __launch_bounds__(256) void out_reg(const void* __restrict__ bout,
                                               int fb,
                                               float* __restrict__ ws,
                                               float* __restrict__ out) {
    const int* flags = (const int*)ws;
    const u16* af = (const u16*)(ws + OFF_AOF);
    const u16* wof = (const u16*)(ws + OFF_WOF);
    int f32b = flags[fb];

    int tid = threadIdx.x;
    int lane = tid & 63, w = tid >> 6;
    int quad = lane >> 4, col = lane & 15;
    int ti4 = blockIdx.x;
    int tn = blockIdx.y * 4 + w;
    int i0 = ti4 * 64;
    int n0 = blockIdx.y * 64;

    f32x4 acc[4];
#pragma unroll
    for (int mt = 0; mt < 4; ++mt) acc[mt] = (f32x4){0.f, 0.f, 0.f, 0.f};

    const u16* bp = wof + (tn * 24) * 512 + lane * 8;
    const u16* ap = af + (ti4 * 4 * 24) * 512 + lane * 8;
#pragma unroll 4
    for (int kc = 0; kc < 24; ++kc) {
        s16x8 bfrag = *(const s16x8*)(bp + kc * 512);
#pragma unroll
        for (int mt = 0; mt < 4; ++mt) {
            s16x8 afrag = *(const s16x8*)(ap + (mt * 24 + kc) * 512);
            acc[mt] = __builtin_amdgcn_mfma_f32_16x16x32_bf16(afrag, bfrag, acc[mt], 0, 0, 0);
        }
    }

    int c = n0 + w * 16 + col;
    float bias = ldin(bout, c, f32b);
#pragma unroll
    for (int mt = 0; mt < 4; ++mt) {
#pragma unroll
        for (int r = 0; r < 4; ++r) {
            int i = i0 + mt * 16 + quad * 4 + r;
            out[i * CDIM + c] = acc[mt][r] + bias;
        }
    }
}

// ---------------------------------------------------------------------------
extern "C" void kernel_launch(void* const* d_in, const int* in_sizes, int n_in,
                              void* d_out, int out_size, void* d_ws, size_t ws_size,
                              hipStream_t stream) {
    float* out = (float*)d_out;
    float* ws = (float*)d_ws;

    const int want[9] = {1179648, 393216, 393216, 589824, 589824, 768, 49152, 512, 512};
    int role2in[9], used[9] = {0};
    bool ok = (n_in == 9);
    if (ok) {
        for (int r = 0; r < 9; ++r) {
            int found = -1;
            for (int i = 0; i < 9 && found < 0; ++i)
                if (!used[i] && in_sizes[i] == want[r]) found = i;
            if (found < 0) { ok = false; break; }
            used[found] = 1;
            role2in[r] = found;
        }
    }
    if (!ok) for (int r = 0; r < 9; ++r) role2in[r] = r;

    const void* x    = d_in[role2in[0]];
    const void* Wq   = d_in[role2in[1]];
    const void* Wk   = d_in[role2in[2]];
    const void* Wv   = d_in[role2in[3]];
    const void* Wout = d_in[role2in[4]];
    const void* bout = d_in[role2in[5]];
    const void* Wpos = d_in[role2in[6]];
    const void* rcb  = d_in[role2in[7]];
    const void* rpb  = d_in[role2in[8]];

    In9 s;
    for (int i = 0; i < 9; ++i) { s.p[i] = d_in[i]; s.n[i] = in_sizes[i]; }
    hipLaunchKernelGGL(probe_all, dim3(9), dim3(256), 0, stream, s, (int*)ws);

    hipLaunchKernelGGL(prep, dim3(2507), dim3(256), 0, stream,
                       x, Wq, Wk, Wv, Wout, Wpos,
                       role2in[0], role2in[1], role2in[2], role2in[3],
                       role2in[4], role2in[6], ws);
    hipLaunchKernelGGL(qkv_reg, dim3(24, 28), dim3(256), 0, stream,
                       rcb, rpb, role2in[7], role2in[8], ws);
    hipLaunchKernelGGL(attn_mfma, dim3(768), dim3(256), 0, stream, ws);
    hipLaunchKernelGGL(out_reg, dim3(24, 12), dim3(256), 0, stream,
                       bout, role2in[5], ws, out);
}

// Round 13
// 158.238 us; speedup vs baseline: 1.5037x; 1.1709x over previous
//
#include <hip/hip_runtime.h>
#include <stdint.h>

#define NTOK 1536
#define CDIM 768
#define NH 8
#define DKH 64
#define DVH 96
#define NF 96

typedef unsigned short u16;
typedef __attribute__((ext_vector_type(8))) short s16x8;   // 8 bf16 (4 VGPRs)
typedef __attribute__((ext_vector_type(4))) float f32x4;   // MFMA acc

#define LGKM0() asm volatile("s_waitcnt lgkmcnt(0)" ::: "memory")

__device__ __forceinline__ float b2f(u16 u) {
    union { uint32_t i; float f; } v; v.i = ((uint32_t)u) << 16; return v.f;
}
__device__ __forceinline__ u16 f2b(float f) {
    union { float f; uint32_t i; } v; v.f = f;
    uint32_t x = v.i;
    return (u16)((x + 0x7FFFu + ((x >> 16) & 1u)) >> 16);
}
__device__ __forceinline__ float ldin(const void* p, int i, int f32) {
    return f32 ? ((const float*)p)[i] : b2f(((const u16*)p)[i]);
}

// Fragment-major layout: within a (16 rows x 32 k) block of 512 bf16,
// element (m, kk) sits at ((kk>>3)*16 + m)*8 + (kk&7).
#define FIDX(m, kk) ((((kk) >> 3) * 16 + (m)) * 8 + ((kk) & 7))

// ---------------------------------------------------------------------------
// ws layout (float offsets). flags[0..8] at ws[0..8]. ~14.8 MB.
// ---------------------------------------------------------------------------
#define OFF_WSUF 16
#define OFF_S11  (OFF_WSUF + 5632)
#define OFF_QF   (OFF_S11 + 147456)     // u16: qfrag  (h,ti:96,kc2:2)  A-frags
#define OFF_KF   (OFF_QF + 393216)      // u16: kfrag  (h,tj:96,kc2:2)  B-frags
#define OFF_VF   (OFF_KF + 393216)      // u16: vfrag  (h,jc:48,nt:6)   B-frags
#define OFF_AOF  (OFF_VF + 589824)      // u16: aofrag (ti:96,kc:24)    A-frags
#define OFF_XF   (OFF_AOF + 589824)     // u16: xfrag  (ti:96,kc:24)    A-frags
#define OFF_WF   (OFF_XF + 589824)      // u16: wfrag  (tn:112,kc:24)   B-frags
#define OFF_WOF  (OFF_WF + 688128)      // u16: wofrag (tn:48,kc:24)    B-frags

struct In9 { const void* p[9]; int n[9]; };

// ---------------------------------------------------------------------------
// Kernel P: per-input dtype probe. flags[k]=1 iff fp32.
// ---------------------------------------------------------------------------
__global__ __launch_bounds__(256) void probe_all(In9 s, int* __restrict__ flags) {
    __shared__ int bad;
    int k = blockIdx.x;
    if (threadIdx.x == 0) bad = 0;
    __syncthreads();
    const u16* a = (const u16*)s.p[k];
    int n = s.n[k];
    if (n > 2048) n = 2048;
    int my = 0;
    for (int i = threadIdx.x; i < n; i += 256) {
        float v = b2f(a[i]);
        if (!(fabsf(v) < 1e6f)) my = 1;
    }
    if (my) atomicOr(&bad, 1);
    __syncthreads();
    if (threadIdx.x == 0) flags[k] = bad;
}

// ---------------------------------------------------------------------------
// Kernel PR: build fragment buffers.  NO LDS, NO barriers, high MLP:
//   bx [0,144):      xfrag — wave handles 4 chunks; 8 independent 16B loads.
//   bx [144,1104):   weight frags — wave = 1 chunk; lane does 8 independent
//                    scalar loads (column gather, 64B-coalesced per group)
//                    then ONE 16B store.  B-frag built directly in registers.
//   bx [1104,1115):  wsuf row t (4-way partial sums for ILP).
// ---------------------------------------------------------------------------
__global__ __launch_bounds__(256) void prep(const void* __restrict__ x,
                                            const void* __restrict__ Wq,
                                            const void* __restrict__ Wk,
                                            const void* __restrict__ Wv,
                                            const void* __restrict__ Wout,
                                            const void* __restrict__ Wpos,
                                            int fx, int fq, int fk, int fv,
                                            int fw, int fpos,
                                            float* __restrict__ ws) {
    const int* flags = (const int*)ws;
    int bx = blockIdx.x, tid = threadIdx.x;
    int wv = tid >> 6, L = tid & 63;

    if (bx < 144) {
        // ---- xfrag: 4 chunks per wave, all loads issued before stores ----
        int f = flags[fx];
        u16* dst = (u16*)(ws + OFF_XF);
        int cbase = (bx * 4 + wv) * 4;
        int m = L & 15, kq = L >> 4;
        int srcs[4];
#pragma unroll
        for (int c = 0; c < 4; ++c) {
            int ch = cbase + c;
            int ti = ch / 24, kc = ch % 24;
            srcs[c] = (ti * 16 + m) * CDIM + kc * 32 + kq * 8;
        }
        if (f) {
            float4 a[4][2];
#pragma unroll
            for (int c = 0; c < 4; ++c) {
                const float* xp = (const float*)x + srcs[c];
                a[c][0] = *(const float4*)(xp);
                a[c][1] = *(const float4*)(xp + 4);
            }
#pragma unroll
            for (int c = 0; c < 4; ++c) {
                union { u16 u[8]; uint4 v; } pk;
                pk.u[0] = f2b(a[c][0].x); pk.u[1] = f2b(a[c][0].y);
                pk.u[2] = f2b(a[c][0].z); pk.u[3] = f2b(a[c][0].w);
                pk.u[4] = f2b(a[c][1].x); pk.u[5] = f2b(a[c][1].y);
                pk.u[6] = f2b(a[c][1].z); pk.u[7] = f2b(a[c][1].w);
                *(uint4*)(dst + (cbase + c) * 512 + L * 8) = pk.v;
            }
        } else {
            uint4 v[4];
#pragma unroll
            for (int c = 0; c < 4; ++c) v[c] = *(const uint4*)((const u16*)x + srcs[c]);
#pragma unroll
            for (int c = 0; c < 4; ++c)
                *(uint4*)(dst + (cbase + c) * 512 + L * 8) = v[c];
        }
        return;
    }
    if (bx < 1104) {
        // ---- weight frag chunk: direct register gather ----
        int c = (bx - 144) * 4 + wv;    // [0, 3840)
        const void* src; int ld, cn0, f; u16* dst; int kc;
        if (c < 2688) {
            int tn = c / 24; kc = c % 24;
            int n0 = tn * 16;
            dst = (u16*)(ws + OFF_WF) + c * 512;
            if (n0 < 512)       { src = Wq; ld = 512;  cn0 = n0;        f = flags[fq]; }
            else if (n0 < 1024) { src = Wk; ld = 512;  cn0 = n0 - 512;  f = flags[fk]; }
            else                { src = Wv; ld = CDIM; cn0 = n0 - 1024; f = flags[fv]; }
        } else {
            int c2 = c - 2688;
            int tn = c2 / 24; kc = c2 % 24;
            dst = (u16*)(ws + OFF_WOF) + c2 * 512;
            src = Wout; ld = CDIM; cn0 = tn * 16; f = flags[fw];
        }
        int nn = L & 15, kq = L >> 4;
        int base = (kc * 32 + kq * 8) * ld + cn0 + nn;
        union { u16 u[8]; uint4 v; } pk;
        if (f) {
            const float* sp = (const float*)src + base;
            float a0 = sp[0], a1 = sp[ld], a2 = sp[2 * ld], a3 = sp[3 * ld];
            float a4 = sp[4 * ld], a5 = sp[5 * ld], a6 = sp[6 * ld], a7 = sp[7 * ld];
            pk.u[0] = f2b(a0); pk.u[1] = f2b(a1); pk.u[2] = f2b(a2); pk.u[3] = f2b(a3);
            pk.u[4] = f2b(a4); pk.u[5] = f2b(a5); pk.u[6] = f2b(a6); pk.u[7] = f2b(a7);
        } else {
            const u16* sp = (const u16*)src + base;
            pk.u[0] = sp[0]; pk.u[1] = sp[ld]; pk.u[2] = sp[2 * ld]; pk.u[3] = sp[3 * ld];
            pk.u[4] = sp[4 * ld]; pk.u[5] = sp[5 * ld]; pk.u[6] = sp[6 * ld]; pk.u[7] = sp[7 * ld];
        }
        *(uint4*)(dst + L * 8) = pk.v;
        return;
    }
    // ---- wsuf ----
    int t = bx - 1104;
    int f = flags[fpos];
    for (int hd = tid; hd < 512; hd += 256) {
        float s0 = 0.f, s1 = 0.f, s2 = 0.f, s3 = 0.f;
        int f0 = t;
        for (; f0 + 4 <= NF; f0 += 4) {
            s0 += ldin(Wpos, f0 * 512 + hd, f);
            s1 += ldin(Wpos, (f0 + 1) * 512 + hd, f);
            s2 += ldin(Wpos, (f0 + 2) * 512 + hd, f);
            s3 += ldin(Wpos, (f0 + 3) * 512 + hd, f);
        }
        for (; f0 < NF; ++f0) s0 += ldin(Wpos, f0 * 512 + hd, f);
        ws[OFF_WSUF + t * 512 + hd] = (s0 + s1) + (s2 + s3);
    }
}

// ---------------------------------------------------------------------------
// Kernel 1: QKV GEMM, register-direct MFMA with fragment-major operands.
// ---------------------------------------------------------------------------
__global__ __launch_bounds__(256) void qkv_reg(const void* __restrict__ rcb,
                                               const void* __restrict__ rpb,
                                               int fc, int fp,
                                               float* __restrict__ ws) {
    __shared__ float qt[64 * 68];
    __shared__ float rpd[12];
    const int* flags = (const int*)ws;
    const u16* xf = (const u16*)(ws + OFF_XF);
    const u16* wf = (const u16*)(ws + OFF_WF);
    u16* qf = (u16*)(ws + OFF_QF);
    u16* kf = (u16*)(ws + OFF_KF);
    u16* vf = (u16*)(ws + OFF_VF);

    int tid = threadIdx.x;
    int lane = tid & 63, w = tid >> 6;
    int quad = lane >> 4, col = lane & 15;
    int ti4 = blockIdx.x;
    int tn4 = blockIdx.y;
    int tn = tn4 * 4 + w;
    int i0 = ti4 * 64;
    bool isQ = (tn4 < 8);
    int hq = tn4;

    if (isQ && tid < 12) {
        float s = 0.f;
        if (tid < 11) {
            const float* wp = ws + OFF_WSUF + tid * 512 + hq * 64;
            int f32p = flags[fp];
            for (int d = 0; d < 64; ++d) s += ldin(rpb, hq * 64 + d, f32p) * wp[d];
        }
        rpd[tid] = s;
    }

    f32x4 acc[4];
#pragma unroll
    for (int mt = 0; mt < 4; ++mt) acc[mt] = (f32x4){0.f, 0.f, 0.f, 0.f};

    const u16* bp = wf + (tn * 24) * 512 + lane * 8;
    const u16* ap = xf + (ti4 * 4 * 24) * 512 + lane * 8;
#pragma unroll 4
    for (int kc = 0; kc < 24; ++kc) {
        s16x8 bfrag = *(const s16x8*)(bp + kc * 512);
#pragma unroll
        for (int mt = 0; mt < 4; ++mt) {
            s16x8 afrag = *(const s16x8*)(ap + (mt * 24 + kc) * 512);
            acc[mt] = __builtin_amdgcn_mfma_f32_16x16x32_bf16(afrag, bfrag, acc[mt], 0, 0, 0);
        }
    }

    if (isQ) {
#pragma unroll
        for (int mt = 0; mt < 4; ++mt)
#pragma unroll
            for (int r = 0; r < 4; ++r)
                qt[(mt * 16 + quad * 4 + r) * 68 + w * 16 + col] = acc[mt][r] * 0.125f;
        __syncthreads();
        int f32c = flags[fc];
        for (int idx = tid; idx < 64 * 64; idx += 256) {
            int row = idx >> 6, d = idx & 63;
            int ti = ti4 * 4 + (row >> 4), m = row & 15;
            u16 val = f2b(qt[row * 68 + d] + ldin(rcb, hq * 64 + d, f32c));
            qf[((hq * 96 + ti) * 2 + (d >> 5)) * 512 + FIDX(m, d & 31)] = val;
        }
        const float* wsuf = ws + OFF_WSUF;
        float* s11 = ws + OFF_S11;
        for (int idx = tid; idx < 64 * 12; idx += 256) {
            int row = idx / 12, t = idx % 12;
            float s = rpd[t];
            if (t < 11) {
                const float* wp = wsuf + t * 512 + hq * 64;
                const float* qr = qt + row * 68;
                for (int d = 0; d < 64; ++d) s += qr[d] * wp[d];
            }
            s11[(hq * NTOK + i0 + row) * 12 + t] = s;
        }
    } else if (tn < 64) {
        int h = (tn >> 2) - 8;
        int d = ((tn & 3) * 16) + col;
#pragma unroll
        for (int mt = 0; mt < 4; ++mt) {
            int tj = ti4 * 4 + mt;
#pragma unroll
            for (int r = 0; r < 4; ++r) {
                int nn = quad * 4 + r;
                kf[((h * 96 + tj) * 2 + (d >> 5)) * 512 + FIDX(nn, d & 31)] = f2b(acc[mt][r]);
            }
        }
    } else {
        int c = tn * 16 + col - 1024;
        int h = c / 96, d = c % 96;
        int nt = d >> 4, nn = d & 15;
#pragma unroll
        for (int mt = 0; mt < 4; ++mt) {
#pragma unroll
            for (int r = 0; r < 4; ++r) {
                int j = i0 + mt * 16 + quad * 4 + r;
                int jc = j >> 5, kk = j & 31;
                vf[((h * 48 + jc) * 6 + nt) * 512 + FIDX(nn, kk)] = f2b(acc[mt][r]);
            }
        }
    }
}

// ---------------------------------------------------------------------------
// Kernel 3: MFMA flash attention, fixed-offset softmax, fragment-major loads.
// ---------------------------------------------------------------------------
__global__ __launch_bounds__(256) void attn_mfma(float* __restrict__ ws) {
    __shared__ float s11b[192];
    __shared__ alignas(16) u16 pbuf[4][2][16 * 36];
    __shared__ float Om[4][16 * 96];
    __shared__ float lw[4][16];

    const u16* qf = (const u16*)(ws + OFF_QF);
    const u16* kf = (const u16*)(ws + OFF_KF);
    const u16* vf = (const u16*)(ws + OFF_VF);
    const float* s11 = ws + OFF_S11;
    u16* aof = (u16*)(ws + OFF_AOF);

    int h = blockIdx.x & 7;
    int ti = blockIdx.x >> 3;
    int i0 = ti * 16;
    int tid = threadIdx.x;
    int wv = tid >> 6, lane = tid & 63;
    int quad = lane >> 4, col = lane & 15;

    if (tid < 192) s11b[tid] = s11[(h * NTOK + i0 + tid / 12) * 12 + tid % 12];
    const u16* qp = qf + ((h * 96 + ti) * 2) * 512 + lane * 8;
    s16x8 a_lo = *(const s16x8*)(qp);
    s16x8 a_hi = *(const s16x8*)(qp + 512);
    __syncthreads();

    f32x4 O[2][6];
    float lsum[4];
#pragma unroll
    for (int s = 0; s < 2; ++s)
#pragma unroll
        for (int nt = 0; nt < 6; ++nt) O[s][nt] = (f32x4){0.f, 0.f, 0.f, 0.f};
#pragma unroll
    for (int r = 0; r < 4; ++r) lsum[r] = 0.f;

    for (int c = 0; c < 6; ++c) {
        f32x4 S[2][2];
#pragma unroll
        for (int s = 0; s < 2; ++s) {
            int tj0 = wv * 24 + s * 12 + c * 2;
            const u16* kp = kf + ((h * 96 + tj0) * 2) * 512 + lane * 8;
            s16x8 b0lo = *(const s16x8*)(kp);
            s16x8 b0hi = *(const s16x8*)(kp + 512);
            s16x8 b1lo = *(const s16x8*)(kp + 1024);
            s16x8 b1hi = *(const s16x8*)(kp + 1536);
            f32x4 t0 = (f32x4){0.f, 0.f, 0.f, 0.f};
            f32x4 t1 = (f32x4){0.f, 0.f, 0.f, 0.f};
            t0 = __builtin_amdgcn_mfma_f32_16x16x32_bf16(a_lo, b0lo, t0, 0, 0, 0);
            t0 = __builtin_amdgcn_mfma_f32_16x16x32_bf16(a_hi, b0hi, t0, 0, 0, 0);
            t1 = __builtin_amdgcn_mfma_f32_16x16x32_bf16(a_lo, b1lo, t1, 0, 0, 0);
            t1 = __builtin_amdgcn_mfma_f32_16x16x32_bf16(a_hi, b1hi, t1, 0, 0, 0);
            S[s][0] = t0; S[s][1] = t1;
        }
        LGKM0();
#pragma unroll
        for (int s = 0; s < 2; ++s) {
            int j0 = wv * 384 + s * 192 + c * 32;
            int lo1 = j0 - (i0 + 15), lo2 = i0 - (j0 + 31);
            int dmin = lo1 > 0 ? lo1 : (lo2 > 0 ? lo2 : 0);
            int dm1 = i0 + 15 - j0, dm2 = j0 + 31 - i0;
            int dmax = dm1 > dm2 ? dm1 : dm2;
            int tlo = 31 - __builtin_clz(dmin + 1);
            int thi = 31 - __builtin_clz(dmax + 1);
            if (tlo == thi) {
#pragma unroll
                for (int r = 0; r < 4; ++r) {
                    int row = quad * 4 + r;
                    float bv = s11b[row * 12 + tlo] - 12.f;
                    float p0 = __expf(S[s][0][r] + bv);
                    float p1 = __expf(S[s][1][r] + bv);
                    pbuf[wv][s][row * 36 + col] = f2b(p0);
                    pbuf[wv][s][row * 36 + 16 + col] = f2b(p1);
                    lsum[r] += p0 + p1;
                }
            } else {
#pragma unroll
                for (int r = 0; r < 4; ++r) {
                    int row = quad * 4 + r;
                    int ig = i0 + row;
                    int d0 = ig - (j0 + col); d0 = d0 < 0 ? -d0 : d0;
                    int d1 = ig - (j0 + 16 + col); d1 = d1 < 0 ? -d1 : d1;
                    float v0 = S[s][0][r] + s11b[row * 12 + (31 - __builtin_clz(d0 + 1))];
                    float v1 = S[s][1][r] + s11b[row * 12 + (31 - __builtin_clz(d1 + 1))];
                    float p0 = __expf(v0 - 12.f);
                    float p1 = __expf(v1 - 12.f);
                    pbuf[wv][s][row * 36 + col] = f2b(p0);
                    pbuf[wv][s][row * 36 + 16 + col] = f2b(p1);
                    lsum[r] += p0 + p1;
                }
            }
        }
        LGKM0();
#pragma unroll
        for (int s = 0; s < 2; ++s) {
            int jc = wv * 12 + s * 6 + c;
            const u16* pr = &pbuf[wv][s][col * 36 + quad * 8];
            union { s16x8 v; uint2 u2[2]; } pa;
            pa.u2[0] = *(const uint2*)(pr);
            pa.u2[1] = *(const uint2*)(pr + 4);
            const u16* vp = vf + ((h * 48 + jc) * 6) * 512 + lane * 8;
#pragma unroll
            for (int nt = 0; nt < 6; ++nt) {
                s16x8 vfr = *(const s16x8*)(vp + nt * 512);
                O[s][nt] = __builtin_amdgcn_mfma_f32_16x16x32_bf16(pa.v, vfr, O[s][nt], 0, 0, 0);
            }
        }
    }

#pragma unroll
    for (int off = 1; off < 16; off <<= 1)
#pragma unroll
        for (int r = 0; r < 4; ++r) lsum[r] += __shfl_xor(lsum[r], off);
    if (col == 0)
#pragma unroll
        for (int r = 0; r < 4; ++r) lw[wv][quad * 4 + r] = lsum[r];
#pragma unroll
    for (int r = 0; r < 4; ++r) {
        int row = quad * 4 + r;
#pragma unroll
        for (int nt = 0; nt < 6; ++nt)
            Om[wv][row * 96 + nt * 16 + col] = O[0][nt][r] + O[1][nt][r];
    }
    __syncthreads();
    for (int idx = tid; idx < 16 * 96; idx += 256) {
        int row = idx / 96, cc = idx % 96;
        float L = lw[0][row] + lw[1][row] + lw[2][row] + lw[3][row];
        float val = (Om[0][idx] + Om[1][idx] + Om[2][idx] + Om[3][idx]) / L;
        aof[(ti * 24 + h * 3 + (cc >> 5)) * 512 + FIDX(row, cc & 31)] = f2b(val);
    }
}

// ---------------------------------------------------------------------------
// Kernel 4: output GEMM, register-direct MFMA, fragment-major + bias -> fp32.
// ---------------------------------------------------------------------------
__global__ __launch_bounds__(256) void out_reg(const void* __restrict__ bout,
                                               int fb,
                                               float* __restrict__ ws,
                                               float* __restrict__ out) {
    const int* flags = (const int*)ws;
    const u16* af = (const u16*)(ws + OFF_AOF);
    const u16* wof = (const u16*)(ws + OFF_WOF);
    int f32b = flags[fb];

    int tid = threadIdx.x;
    int lane = tid & 63, w = tid >> 6;
    int quad = lane >> 4, col = lane & 15;
    int ti4 = blockIdx.x;
    int tn = blockIdx.y * 4 + w;
    int i0 = ti4 * 64;
    int n0 = blockIdx.y * 64;

    f32x4 acc[4];
#pragma unroll
    for (int mt = 0; mt < 4; ++mt) acc[mt] = (f32x4){0.f, 0.f, 0.f, 0.f};

    const u16* bp = wof + (tn * 24) * 512 + lane * 8;
    const u16* ap = af + (ti4 * 4 * 24) * 512 + lane * 8;
#pragma unroll 4
    for (int kc = 0; kc < 24; ++kc) {
        s16x8 bfrag = *(const s16x8*)(bp + kc * 512);
#pragma unroll
        for (int mt = 0; mt < 4; ++mt) {
            s16x8 afrag = *(const s16x8*)(ap + (mt * 24 + kc) * 512);
            acc[mt] = __builtin_amdgcn_mfma_f32_16x16x32_bf16(afrag, bfrag, acc[mt], 0, 0, 0);
        }
    }

    int c = n0 + w * 16 + col;
    float bias = ldin(bout, c, f32b);
#pragma unroll
    for (int mt = 0; mt < 4; ++mt) {
#pragma unroll
        for (int r = 0; r < 4; ++r) {
            int i = i0 + mt * 16 + quad * 4 + r;
            out[i * CDIM + c] = acc[mt][r] + bias;
        }
    }
}

// ---------------------------------------------------------------------------
extern "C" void kernel_launch(void* const* d_in, const int* in_sizes, int n_in,
                              void* d_out, int out_size, void* d_ws, size_t ws_size,
                              hipStream_t stream) {
    float* out = (float*)d_out;
    float* ws = (float*)d_ws;

    const int want[9] = {1179648, 393216, 393216, 589824, 589824, 768, 49152, 512, 512};
    int role2in[9], used[9] = {0};
    bool ok = (n_in == 9);
    if (ok) {
        for (int r = 0; r < 9; ++r) {
            int found = -1;
            for (int i = 0; i < 9 && found < 0; ++i)
                if (!used[i] && in_sizes[i] == want[r]) found = i;
            if (found < 0) { ok = false; break; }
            used[found] = 1;
            role2in[r] = found;
        }
    }
    if (!ok) for (int r = 0; r < 9; ++r) role2in[r] = r;

    const void* x    = d_in[role2in[0]];
    const void* Wq   = d_in[role2in[1]];
    const void* Wk   = d_in[role2in[2]];
    const void* Wv   = d_in[role2in[3]];
    const void* Wout = d_in[role2in[4]];
    const void* bout = d_in[role2in[5]];
    const void* Wpos = d_in[role2in[6]];
    const void* rcb  = d_in[role2in[7]];
    const void* rpb  = d_in[role2in[8]];

    In9 s;
    for (int i = 0; i < 9; ++i) { s.p[i] = d_in[i]; s.n[i] = in_sizes[i]; }
    hipLaunchKernelGGL(probe_all, dim3(9), dim3(256), 0, stream, s, (int*)ws);

    hipLaunchKernelGGL(prep, dim3(1115), dim3(256), 0, stream,
                       x, Wq, Wk, Wv, Wout, Wpos,
                       role2in[0], role2in[1], role2in[2], role2in[3],
                       role2in[4], role2in[6], ws);
    hipLaunchKernelGGL(qkv_reg, dim3(24, 28), dim3(256), 0, stream,
                       rcb, rpb, role2in[7], role2in[8], ws);
    hipLaunchKernelGGL(attn_mfma, dim3(768), dim3(256), 0, stream, ws);
    hipLaunchKernelGGL(out_reg, dim3(24, 12), dim3(256), 0, stream,
                       bout, role2in[5], ws, out);
}

// Round 15
// 151.349 us; speedup vs baseline: 1.5722x; 1.0455x over previous
//
#include <hip/hip_runtime.h>
#include <stdint.h>

#define NTOK 1536
#define CDIM 768
#define NH 8
#define DKH 64
#define DVH 96
#define NF 96

typedef unsigned short u16;
typedef __attribute__((ext_vector_type(8))) short s16x8;   // 8 bf16 (4 VGPRs)
typedef __attribute__((ext_vector_type(4))) float f32x4;   // MFMA acc

#define LGKM0() asm volatile("s_waitcnt lgkmcnt(0)" ::: "memory")

__device__ __forceinline__ float b2f(u16 u) {
    union { uint32_t i; float f; } v; v.i = ((uint32_t)u) << 16; return v.f;
}
__device__ __forceinline__ u16 f2b(float f) {
    union { float f; uint32_t i; } v; v.f = f;
    uint32_t x = v.i;
    return (u16)((x + 0x7FFFu + ((x >> 16) & 1u)) >> 16);
}
__device__ __forceinline__ float ldin(const void* p, int i, int f32) {
    return f32 ? ((const float*)p)[i] : b2f(((const u16*)p)[i]);
}

// Fragment-major: element (m, kk) of a (16 x 32k) 512-elem block sits at
// ((kk>>3)*16 + m)*8 + (kk&7)  == lane*8 + slot.
#define FIDX(m, kk) ((((kk) >> 3) * 16 + (m)) * 8 + ((kk) & 7))

// ---------------------------------------------------------------------------
// ws layout (float offsets). flags[0..8] at ws[0..8]. ~14.8 MB.
// ---------------------------------------------------------------------------
#define OFF_WSUF 16
#define OFF_S11  (OFF_WSUF + 5632)
#define OFF_QF   (OFF_S11 + 147456)     // u16: qfrag  (h,ti:96,kc2:2)  A-frags
#define OFF_KF   (OFF_QF + 393216)      // u16: kfrag  (h,tj:96,kc2:2)  B-frags
#define OFF_VF   (OFF_KF + 393216)      // u16: vfrag  (h,jc:48,nt:6)   B-frags
#define OFF_AOF  (OFF_VF + 589824)      // u16: aofrag (ti:96,kc:24)    A-frags
#define OFF_XF   (OFF_AOF + 589824)     // u16: xfrag  (ti:96,kc:24)    A-frags
#define OFF_WF   (OFF_XF + 589824)      // u16: wfrag  (tn:112,kc:24)   B-frags
#define OFF_WOF  (OFF_WF + 688128)      // u16: wofrag (tn:48,kc:24)    B-frags

struct In9 { const void* p[9]; int n[9]; };

// ---------------------------------------------------------------------------
// Kernel P: per-input dtype probe. flags[k]=1 iff fp32.
// ---------------------------------------------------------------------------
__global__ __launch_bounds__(256) void probe_all(In9 s, int* __restrict__ flags) {
    __shared__ int bad;
    int k = blockIdx.x;
    if (threadIdx.x == 0) bad = 0;
    __syncthreads();
    const u16* a = (const u16*)s.p[k];
    int n = s.n[k];
    if (n > 2048) n = 2048;
    int my = 0;
    for (int i = threadIdx.x; i < n; i += 256) {
        float v = b2f(a[i]);
        if (!(fabsf(v) < 1e6f)) my = 1;
    }
    if (my) atomicOr(&bad, 1);
    __syncthreads();
    if (threadIdx.x == 0) flags[k] = bad;
}

// ---------------------------------------------------------------------------
// Kernel PR: build fragment buffers.  NO LDS, NO barriers, high MLP.
// ---------------------------------------------------------------------------
__global__ __launch_bounds__(256) void prep(const void* __restrict__ x,
                                            const void* __restrict__ Wq,
                                            const void* __restrict__ Wk,
                                            const void* __restrict__ Wv,
                                            const void* __restrict__ Wout,
                                            const void* __restrict__ Wpos,
                                            int fx, int fq, int fk, int fv,
                                            int fw, int fpos,
                                            float* __restrict__ ws) {
    const int* flags = (const int*)ws;
    int bx = blockIdx.x, tid = threadIdx.x;
    int wv = tid >> 6, L = tid & 63;

    if (bx < 144) {
        int f = flags[fx];
        u16* dst = (u16*)(ws + OFF_XF);
        int cbase = (bx * 4 + wv) * 4;
        int m = L & 15, kq = L >> 4;
        int srcs[4];
#pragma unroll
        for (int c = 0; c < 4; ++c) {
            int ch = cbase + c;
            int ti = ch / 24, kc = ch % 24;
            srcs[c] = (ti * 16 + m) * CDIM + kc * 32 + kq * 8;
        }
        if (f) {
            float4 a[4][2];
#pragma unroll
            for (int c = 0; c < 4; ++c) {
                const float* xp = (const float*)x + srcs[c];
                a[c][0] = *(const float4*)(xp);
                a[c][1] = *(const float4*)(xp + 4);
            }
#pragma unroll
            for (int c = 0; c < 4; ++c) {
                union { u16 u[8]; uint4 v; } pk;
                pk.u[0] = f2b(a[c][0].x); pk.u[1] = f2b(a[c][0].y);
                pk.u[2] = f2b(a[c][0].z); pk.u[3] = f2b(a[c][0].w);
                pk.u[4] = f2b(a[c][1].x); pk.u[5] = f2b(a[c][1].y);
                pk.u[6] = f2b(a[c][1].z); pk.u[7] = f2b(a[c][1].w);
                *(uint4*)(dst + (cbase + c) * 512 + L * 8) = pk.v;
            }
        } else {
            uint4 v[4];
#pragma unroll
            for (int c = 0; c < 4; ++c) v[c] = *(const uint4*)((const u16*)x + srcs[c]);
#pragma unroll
            for (int c = 0; c < 4; ++c)
                *(uint4*)(dst + (cbase + c) * 512 + L * 8) = v[c];
        }
        return;
    }
    if (bx < 1104) {
        int c = (bx - 144) * 4 + wv;
        const void* src; int ld, cn0, f; u16* dst; int kc;
        if (c < 2688) {
            int tn = c / 24; kc = c % 24;
            int n0 = tn * 16;
            dst = (u16*)(ws + OFF_WF) + c * 512;
            if (n0 < 512)       { src = Wq; ld = 512;  cn0 = n0;        f = flags[fq]; }
            else if (n0 < 1024) { src = Wk; ld = 512;  cn0 = n0 - 512;  f = flags[fk]; }
            else                { src = Wv; ld = CDIM; cn0 = n0 - 1024; f = flags[fv]; }
        } else {
            int c2 = c - 2688;
            int tn = c2 / 24; kc = c2 % 24;
            dst = (u16*)(ws + OFF_WOF) + c2 * 512;
            src = Wout; ld = CDIM; cn0 = tn * 16; f = flags[fw];
        }
        int nn = L & 15, kq = L >> 4;
        int base = (kc * 32 + kq * 8) * ld + cn0 + nn;
        union { u16 u[8]; uint4 v; } pk;
        if (f) {
            const float* sp = (const float*)src + base;
            float a0 = sp[0], a1 = sp[ld], a2 = sp[2 * ld], a3 = sp[3 * ld];
            float a4 = sp[4 * ld], a5 = sp[5 * ld], a6 = sp[6 * ld], a7 = sp[7 * ld];
            pk.u[0] = f2b(a0); pk.u[1] = f2b(a1); pk.u[2] = f2b(a2); pk.u[3] = f2b(a3);
            pk.u[4] = f2b(a4); pk.u[5] = f2b(a5); pk.u[6] = f2b(a6); pk.u[7] = f2b(a7);
        } else {
            const u16* sp = (const u16*)src + base;
            pk.u[0] = sp[0]; pk.u[1] = sp[ld]; pk.u[2] = sp[2 * ld]; pk.u[3] = sp[3 * ld];
            pk.u[4] = sp[4 * ld]; pk.u[5] = sp[5 * ld]; pk.u[6] = sp[6 * ld]; pk.u[7] = sp[7 * ld];
        }
        *(uint4*)(dst + L * 8) = pk.v;
        return;
    }
    int t = bx - 1104;
    int f = flags[fpos];
    for (int hd = tid; hd < 512; hd += 256) {
        float s0 = 0.f, s1 = 0.f, s2 = 0.f, s3 = 0.f;
        int f0 = t;
        for (; f0 + 4 <= NF; f0 += 4) {
            s0 += ldin(Wpos, f0 * 512 + hd, f);
            s1 += ldin(Wpos, (f0 + 1) * 512 + hd, f);
            s2 += ldin(Wpos, (f0 + 2) * 512 + hd, f);
            s3 += ldin(Wpos, (f0 + 3) * 512 + hd, f);
        }
        for (; f0 < NF; ++f0) s0 += ldin(Wpos, f0 * 512 + hd, f);
        ws[OFF_WSUF + t * 512 + hd] = (s0 + s1) + (s2 + s3);
    }
}

// ---------------------------------------------------------------------------
// Kernel 1: QKV GEMM, register-direct MFMA.  Q-block epilogue MFMA-based:
// S11 = q_scaled . wsuf^T via 2 MFMAs (wsuf^T B-frag built in registers,
// zero-padded t>=11); qf written as frag-structured LDS reads.
// ---------------------------------------------------------------------------
__global__ __launch_bounds__(256) void qkv_reg(const void* __restrict__ rcb,
                                               const void* __restrict__ rpb,
                                               int fc, int fp,
                                               float* __restrict__ ws) {
    __shared__ float qt[64 * 68];
    __shared__ float rpd[12];
    const int* flags = (const int*)ws;
    const u16* xf = (const u16*)(ws + OFF_XF);
    const u16* wf = (const u16*)(ws + OFF_WF);
    u16* qf = (u16*)(ws + OFF_QF);
    u16* kf = (u16*)(ws + OFF_KF);
    u16* vf = (u16*)(ws + OFF_VF);

    int tid = threadIdx.x;
    int lane = tid & 63, w = tid >> 6;
    int quad = lane >> 4, col = lane & 15;
    int ti4 = blockIdx.x;
    int tn4 = blockIdx.y;
    int tn = tn4 * 4 + w;
    int i0 = ti4 * 64;
    bool isQ = (tn4 < 8);
    int hq = tn4;

    // Q-blocks: wsuf^T B-frags in registers (t = col, k = d)
    s16x8 bw0, bw1;
    if (isQ) {
        int t = lane & 15, kq = lane >> 4;
        union { u16 u[8]; s16x8 v; } p0, p1;
#pragma unroll
        for (int j = 0; j < 8; ++j) {
            float v0 = 0.f, v1 = 0.f;
            if (t < 11) {
                v0 = ws[OFF_WSUF + t * 512 + hq * 64 + kq * 8 + j];
                v1 = ws[OFF_WSUF + t * 512 + hq * 64 + 32 + kq * 8 + j];
            }
            p0.u[j] = f2b(v0); p1.u[j] = f2b(v1);
        }
        bw0 = p0.v; bw1 = p1.v;
        if (tid < 12) {
            float s = 0.f;
            if (tid < 11) {
                const float* wp = ws + OFF_WSUF + tid * 512 + hq * 64;
                int f32p = flags[fp];
                for (int d = 0; d < 64; ++d) s += ldin(rpb, hq * 64 + d, f32p) * wp[d];
            }
            rpd[tid] = s;
        }
    }

    f32x4 acc[4];
#pragma unroll
    for (int mt = 0; mt < 4; ++mt) acc[mt] = (f32x4){0.f, 0.f, 0.f, 0.f};

    const u16* bp = wf + (tn * 24) * 512 + lane * 8;
    const u16* ap = xf + (ti4 * 4 * 24) * 512 + lane * 8;
#pragma unroll 4
    for (int kc = 0; kc < 24; ++kc) {
        s16x8 bfrag = *(const s16x8*)(bp + kc * 512);
#pragma unroll
        for (int mt = 0; mt < 4; ++mt) {
            s16x8 afrag = *(const s16x8*)(ap + (mt * 24 + kc) * 512);
            acc[mt] = __builtin_amdgcn_mfma_f32_16x16x32_bf16(afrag, bfrag, acc[mt], 0, 0, 0);
        }
    }

    if (isQ) {
#pragma unroll
        for (int mt = 0; mt < 4; ++mt)
#pragma unroll
            for (int r = 0; r < 4; ++r)
                qt[(mt * 16 + quad * 4 + r) * 68 + w * 16 + col] = acc[mt][r] * 0.125f;
        __syncthreads();
        int f32c = flags[fc];
        int m = lane & 15, kq = lane >> 4;
#pragma unroll
        for (int kc2 = 0; kc2 < 2; ++kc2) {
            union { u16 u[8]; uint4 v; } pk;
#pragma unroll
            for (int j = 0; j < 8; ++j) {
                int d = kc2 * 32 + kq * 8 + j;
                pk.u[j] = f2b(qt[(w * 16 + m) * 68 + d] + ldin(rcb, hq * 64 + d, f32c));
            }
            *(uint4*)(qf + (((hq * 96 + ti4 * 4 + w) * 2 + kc2) * 512) + lane * 8) = pk.v;
        }
        union { u16 u[8]; s16x8 v; } qa0, qa1;
#pragma unroll
        for (int j = 0; j < 8; ++j) {
            qa0.u[j] = f2b(qt[(w * 16 + m) * 68 + kq * 8 + j]);
            qa1.u[j] = f2b(qt[(w * 16 + m) * 68 + 32 + kq * 8 + j]);
        }
        f32x4 s11a = (f32x4){0.f, 0.f, 0.f, 0.f};
        s11a = __builtin_amdgcn_mfma_f32_16x16x32_bf16(qa0.v, bw0, s11a, 0, 0, 0);
        s11a = __builtin_amdgcn_mfma_f32_16x16x32_bf16(qa1.v, bw1, s11a, 0, 0, 0);
        if (col < 12) {
            float rp = rpd[col];
            float* s11 = ws + OFF_S11;
#pragma unroll
            for (int r = 0; r < 4; ++r)
                s11[(hq * NTOK + i0 + w * 16 + quad * 4 + r) * 12 + col] = s11a[r] + rp;
        }
    } else if (tn < 64) {
        int h = (tn >> 2) - 8;
        int d = ((tn & 3) * 16) + col;
#pragma unroll
        for (int mt = 0; mt < 4; ++mt) {
            int tj = ti4 * 4 + mt;
#pragma unroll
            for (int r = 0; r < 4; ++r) {
                int nn = quad * 4 + r;
                kf[((h * 96 + tj) * 2 + (d >> 5)) * 512 + FIDX(nn, d & 31)] = f2b(acc[mt][r]);
            }
        }
    } else {
        int c = tn * 16 + col - 1024;
        int h = c / 96, d = c % 96;
        int nt = d >> 4, nn = d & 15;
#pragma unroll
        for (int mt = 0; mt < 4; ++mt) {
#pragma unroll
            for (int r = 0; r < 4; ++r) {
                int j = i0 + mt * 16 + quad * 4 + r;
                int jc = j >> 5, kk = j & 31;
                vf[((h * 48 + jc) * 6 + nt) * 512 + FIDX(nn, kk)] = f2b(acc[mt][r]);
            }
        }
    }
}

// ---------------------------------------------------------------------------
// Kernel 3: MFMA flash attention.  8 waves/block (512 thr), wave = 192 keys
// (6 chunks x 32), single stream; fixed-offset softmax; frag-major loads;
// per-wave pbuf + lgkmcnt fences; 8-way add-merge at end.
// ---------------------------------------------------------------------------
__global__ __launch_bounds__(512) void attn_mfma(float* __restrict__ ws) {
    __shared__ float s11b[192];
    __shared__ alignas(16) u16 pbuf[8][16 * 36];
    __shared__ float Om[8][16 * 96];
    __shared__ float lw[8][16];

    const u16* qf = (const u16*)(ws + OFF_QF);
    const u16* kf = (const u16*)(ws + OFF_KF);
    const u16* vf = (const u16*)(ws + OFF_VF);
    const float* s11 = ws + OFF_S11;
    u16* aof = (u16*)(ws + OFF_AOF);

    int h = blockIdx.x & 7;               // XCD-affine
    int ti = blockIdx.x >> 3;
    int i0 = ti * 16;
    int tid = threadIdx.x;
    int wv = tid >> 6, lane = tid & 63;
    int quad = lane >> 4, col = lane & 15;

    if (tid < 192) s11b[tid] = s11[(h * NTOK + i0 + tid / 12) * 12 + tid % 12];
    const u16* qp = qf + ((h * 96 + ti) * 2) * 512 + lane * 8;
    s16x8 a_lo = *(const s16x8*)(qp);
    s16x8 a_hi = *(const s16x8*)(qp + 512);
    __syncthreads();

    f32x4 O[6];
    float lsum[4];
#pragma unroll
    for (int nt = 0; nt < 6; ++nt) O[nt] = (f32x4){0.f, 0.f, 0.f, 0.f};
#pragma unroll
    for (int r = 0; r < 4; ++r) lsum[r] = 0.f;

    for (int c = 0; c < 6; ++c) {
        int tj0 = wv * 12 + c * 2;
        const u16* kp = kf + ((h * 96 + tj0) * 2) * 512 + lane * 8;
        s16x8 b0lo = *(const s16x8*)(kp);
        s16x8 b0hi = *(const s16x8*)(kp + 512);
        s16x8 b1lo = *(const s16x8*)(kp + 1024);
        s16x8 b1hi = *(const s16x8*)(kp + 1536);
        f32x4 t0 = (f32x4){0.f, 0.f, 0.f, 0.f};
        f32x4 t1 = (f32x4){0.f, 0.f, 0.f, 0.f};
        t0 = __builtin_amdgcn_mfma_f32_16x16x32_bf16(a_lo, b0lo, t0, 0, 0, 0);
        t0 = __builtin_amdgcn_mfma_f32_16x16x32_bf16(a_hi, b0hi, t0, 0, 0, 0);
        t1 = __builtin_amdgcn_mfma_f32_16x16x32_bf16(a_lo, b1lo, t1, 0, 0, 0);
        t1 = __builtin_amdgcn_mfma_f32_16x16x32_bf16(a_hi, b1hi, t1, 0, 0, 0);

        LGKM0();  // drain previous iter's pbuf reads before overwrite
        int j0 = wv * 192 + c * 32;
        int lo1 = j0 - (i0 + 15), lo2 = i0 - (j0 + 31);
        int dmin = lo1 > 0 ? lo1 : (lo2 > 0 ? lo2 : 0);
        int dm1 = i0 + 15 - j0, dm2 = j0 + 31 - i0;
        int dmax = dm1 > dm2 ? dm1 : dm2;
        int tlo = 31 - __builtin_clz(dmin + 1);
        int thi = 31 - __builtin_clz(dmax + 1);
        if (tlo == thi) {
#pragma unroll
            for (int r = 0; r < 4; ++r) {
                int row = quad * 4 + r;
                float bv = s11b[row * 12 + tlo] - 12.f;
                float p0 = __expf(t0[r] + bv);
                float p1 = __expf(t1[r] + bv);
                pbuf[wv][row * 36 + col] = f2b(p0);
                pbuf[wv][row * 36 + 16 + col] = f2b(p1);
                lsum[r] += p0 + p1;
            }
        } else {
#pragma unroll
            for (int r = 0; r < 4; ++r) {
                int row = quad * 4 + r;
                int ig = i0 + row;
                int d0 = ig - (j0 + col); d0 = d0 < 0 ? -d0 : d0;
                int d1 = ig - (j0 + 16 + col); d1 = d1 < 0 ? -d1 : d1;
                float v0 = t0[r] + s11b[row * 12 + (31 - __builtin_clz(d0 + 1))];
                float v1 = t1[r] + s11b[row * 12 + (31 - __builtin_clz(d1 + 1))];
                float p0 = __expf(v0 - 12.f);
                float p1 = __expf(v1 - 12.f);
                pbuf[wv][row * 36 + col] = f2b(p0);
                pbuf[wv][row * 36 + 16 + col] = f2b(p1);
                lsum[r] += p0 + p1;
            }
        }
        LGKM0();  // pbuf writes visible to this wave
        int jc = wv * 6 + c;
        const u16* pr = &pbuf[wv][col * 36 + quad * 8];
        union { s16x8 v; uint2 u2[2]; } pa;
        pa.u2[0] = *(const uint2*)(pr);
        pa.u2[1] = *(const uint2*)(pr + 4);
        const u16* vp = vf + ((h * 48 + jc) * 6) * 512 + lane * 8;
#pragma unroll
        for (int nt = 0; nt < 6; ++nt) {
            s16x8 vfr = *(const s16x8*)(vp + nt * 512);
            O[nt] = __builtin_amdgcn_mfma_f32_16x16x32_bf16(pa.v, vfr, O[nt], 0, 0, 0);
        }
    }

#pragma unroll
    for (int off = 1; off < 16; off <<= 1)
#pragma unroll
        for (int r = 0; r < 4; ++r) lsum[r] += __shfl_xor(lsum[r], off);
    if (col == 0)
#pragma unroll
        for (int r = 0; r < 4; ++r) lw[wv][quad * 4 + r] = lsum[r];
#pragma unroll
    for (int r = 0; r < 4; ++r) {
        int row = quad * 4 + r;
#pragma unroll
        for (int nt = 0; nt < 6; ++nt)
            Om[wv][row * 96 + nt * 16 + col] = O[nt][r];
    }
    __syncthreads();
    for (int idx = tid; idx < 16 * 96; idx += 512) {
        int row = idx / 96, cc = idx % 96;
        float L = 0.f, val = 0.f;
#pragma unroll
        for (int v = 0; v < 8; ++v) { L += lw[v][row]; val += Om[v][idx]; }
        aof[(ti * 24 + h * 3 + (cc >> 5)) * 512 + FIDX(row, cc & 31)] = f2b(val / L);
    }
}

// ---------------------------------------------------------------------------
// Kernel 4: output GEMM, register-direct MFMA, fragment-major + bias -> fp32.
// ---------------------------------------------------------------------------
__global__ __launch_bounds__(256) void out_reg(const void* __restrict__ bout,
                                               int fb,
                                               float* __restrict__ ws,
                                               float* __restrict__ out) {
    const int* flags = (const int*)ws;
    const u16* af = (const u16*)(ws + OFF_AOF);
    const u16* wof = (const u16*)(ws + OFF_WOF);
    int f32b = flags[fb];

    int tid = threadIdx.x;
    int lane = tid & 63, w = tid >> 6;
    int quad = lane >> 4, col = lane & 15;
    int ti4 = blockIdx.x;
    int tn = blockIdx.y * 4 + w;
    int i0 = ti4 * 64;
    int n0 = blockIdx.y * 64;

    f32x4 acc[4];
#pragma unroll
    for (int mt = 0; mt < 4; ++mt) acc[mt] = (f32x4){0.f, 0.f, 0.f, 0.f};

    const u16* bp = wof + (tn * 24) * 512 + lane * 8;
    const u16* ap = af + (ti4 * 4 * 24) * 512 + lane * 8;
#pragma unroll 4
    for (int kc = 0; kc < 24; ++kc) {
        s16x8 bfrag = *(const s16x8*)(bp + kc * 512);
#pragma unroll
        for (int mt = 0; mt < 4; ++mt) {
            s16x8 afrag = *(const s16x8*)(ap + (mt * 24 + kc) * 512);
            acc[mt] = __builtin_amdgcn_mfma_f32_16x16x32_bf16(afrag, bfrag, acc[mt], 0, 0, 0);
        }
    }

    int c = n0 + w * 16 + col;
    float bias = ldin(bout, c, f32b);
#pragma unroll
    for (int mt = 0; mt < 4; ++mt) {
#pragma unroll
        for (int r = 0; r < 4; ++r) {
            int i = i0 + mt * 16 + quad * 4 + r;
            out[i * CDIM + c] = acc[mt][r] + bias;
        }
    }
}

// ---------------------------------------------------------------------------
extern "C" void kernel_launch(void* const* d_in, const int* in_sizes, int n_in,
                              void* d_out, int out_size, void* d_ws, size_t ws_size,
                              hipStream_t stream) {
    float* out = (float*)d_out;
    float* ws = (float*)d_ws;

    const int want[9] = {1179648, 393216, 393216, 589824, 589824, 768, 49152, 512, 512};
    int role2in[9], used[9] = {0};
    bool ok = (n_in == 9);
    if (ok) {
        for (int r = 0; r < 9; ++r) {
            int found = -1;
            for (int i = 0; i < 9 && found < 0; ++i)
                if (!used[i] && in_sizes[i] == want[r]) found = i;
            if (found < 0) { ok = false; break; }
            used[found] = 1;
            role2in[r] = found;
        }
    }
    if (!ok) for (int r = 0; r < 9; ++r) role2in[r] = r;

    const void* x    = d_in[role2in[0]];
    const void* Wq   = d_in[role2in[1]];
    const void* Wk   = d_in[role2in[2]];
    const void* Wv   = d_in[role2in[3]];
    const void* Wout = d_in[role2in[4]];
    const void* bout = d_in[role2in[5]];
    const void* Wpos = d_in[role2in[6]];
    const void* rcb  = d_in[role2in[7]];
    const void* rpb  = d_in[role2in[8]];

    In9 s;
    for (int i = 0; i < 9; ++i) { s.p[i] = d_in[i]; s.n[i] = in_sizes[i]; }
    hipLaunchKernelGGL(probe_all, dim3(9), dim3(256), 0, stream, s, (int*)ws);

    hipLaunchKernelGGL(prep, dim3(1115), dim3(256), 0, stream,
                       x, Wq, Wk, Wv, Wout, Wpos,
                       role2in[0], role2in[1], role2in[2], role2in[3],
                       role2in[4], role2in[6], ws);
    hipLaunchKernelGGL(qkv_reg, dim3(24, 28), dim3(256), 0, stream,
                       rcb, rpb, role2in[7], role2in[8], ws);
    hipLaunchKernelGGL(attn_mfma, dim3(768), dim3(512), 0, stream, ws);
    hipLaunchKernelGGL(out_reg, dim3(24, 12), dim3(256), 0, stream,
                       bout, role2in[5], ws, out);
}

// Round 16
// 148.013 us; speedup vs baseline: 1.6076x; 1.0225x over previous
//
#include <hip/hip_runtime.h>
#include <stdint.h>

#define NTOK 1536
#define CDIM 768
#define NH 8
#define DKH 64
#define DVH 96
#define NF 96

typedef unsigned short u16;
typedef __attribute__((ext_vector_type(8))) short s16x8;   // 8 bf16 (4 VGPRs)
typedef __attribute__((ext_vector_type(4))) float f32x4;   // MFMA acc

__device__ __forceinline__ float b2f(u16 u) {
    union { uint32_t i; float f; } v; v.i = ((uint32_t)u) << 16; return v.f;
}
__device__ __forceinline__ u16 f2b(float f) {
    union { float f; uint32_t i; } v; v.f = f;
    uint32_t x = v.i;
    return (u16)((x + 0x7FFFu + ((x >> 16) & 1u)) >> 16);
}
__device__ __forceinline__ float ldin(const void* p, int i, int f32) {
    return f32 ? ((const float*)p)[i] : b2f(((const u16*)p)[i]);
}

// Inline wave-uniform dtype probe: scans first 256 u16 words.  A true-bf16
// buffer never decodes |v|>=1e6; fp32 mantissa-low words do w.p. ~0.42 each
// (~128 of the 256 samples) -> miss prob ~3e-29.  Returns 1 iff fp32.
__device__ __forceinline__ int probe_f32(const void* p) {
    const u16* a = (const u16*)p;
    int lane = threadIdx.x & 63;
    int bad = 0;
#pragma unroll
    for (int t = 0; t < 4; ++t) {
        float v = b2f(a[lane + t * 64]);
        if (!(fabsf(v) < 1e6f)) bad = 1;
    }
    return __ballot(bad) != 0ull;
}

// Fragment-major: element (m, kk) of a (16 x 32k) 512-elem block sits at
// ((kk>>3)*16 + m)*8 + (kk&7)  == lane*8 + slot.
#define FIDX(m, kk) ((((kk) >> 3) * 16 + (m)) * 8 + ((kk) & 7))

// ---------------------------------------------------------------------------
// ws layout (float offsets). ~14.8 MB.
// ---------------------------------------------------------------------------
#define OFF_WSUF 16
#define OFF_S11  (OFF_WSUF + 5632)
#define OFF_QF   (OFF_S11 + 147456)     // u16: qfrag  (h,ti:96,kc2:2)  A-frags
#define OFF_KF   (OFF_QF + 393216)      // u16: kfrag  (h,tj:96,kc2:2)  B-frags
#define OFF_VF   (OFF_KF + 393216)      // u16: vfrag  (h,jc:48,nt:6)   B-frags
#define OFF_AOF  (OFF_VF + 589824)      // u16: aofrag (ti:96,kc:24)    A-frags
#define OFF_XF   (OFF_AOF + 589824)     // u16: xfrag  (ti:96,kc:24)    A-frags
#define OFF_WF   (OFF_XF + 589824)      // u16: wfrag  (tn:112,kc:24)   B-frags
#define OFF_WOF  (OFF_WF + 688128)      // u16: wofrag (tn:48,kc:24)    B-frags

// ---------------------------------------------------------------------------
// Kernel PR: build fragment buffers.  NO LDS, NO barriers, high MLP.
// Dtype probes inlined per block (no probe kernel / flags dependency).
// ---------------------------------------------------------------------------
__global__ __launch_bounds__(256) void prep(const void* __restrict__ x,
                                            const void* __restrict__ Wq,
                                            const void* __restrict__ Wk,
                                            const void* __restrict__ Wv,
                                            const void* __restrict__ Wout,
                                            const void* __restrict__ Wpos,
                                            float* __restrict__ ws) {
    int bx = blockIdx.x, tid = threadIdx.x;
    int wv = tid >> 6, L = tid & 63;

    if (bx < 144) {
        int f = probe_f32(x);
        u16* dst = (u16*)(ws + OFF_XF);
        int cbase = (bx * 4 + wv) * 4;
        int m = L & 15, kq = L >> 4;
        int srcs[4];
#pragma unroll
        for (int c = 0; c < 4; ++c) {
            int ch = cbase + c;
            int ti = ch / 24, kc = ch % 24;
            srcs[c] = (ti * 16 + m) * CDIM + kc * 32 + kq * 8;
        }
        if (f) {
            float4 a[4][2];
#pragma unroll
            for (int c = 0; c < 4; ++c) {
                const float* xp = (const float*)x + srcs[c];
                a[c][0] = *(const float4*)(xp);
                a[c][1] = *(const float4*)(xp + 4);
            }
#pragma unroll
            for (int c = 0; c < 4; ++c) {
                union { u16 u[8]; uint4 v; } pk;
                pk.u[0] = f2b(a[c][0].x); pk.u[1] = f2b(a[c][0].y);
                pk.u[2] = f2b(a[c][0].z); pk.u[3] = f2b(a[c][0].w);
                pk.u[4] = f2b(a[c][1].x); pk.u[5] = f2b(a[c][1].y);
                pk.u[6] = f2b(a[c][1].z); pk.u[7] = f2b(a[c][1].w);
                *(uint4*)(dst + (cbase + c) * 512 + L * 8) = pk.v;
            }
        } else {
            uint4 v[4];
#pragma unroll
            for (int c = 0; c < 4; ++c) v[c] = *(const uint4*)((const u16*)x + srcs[c]);
#pragma unroll
            for (int c = 0; c < 4; ++c)
                *(uint4*)(dst + (cbase + c) * 512 + L * 8) = v[c];
        }
        return;
    }
    if (bx < 1104) {
        int c = (bx - 144) * 4 + wv;
        const void* src; int ld, cn0; u16* dst; int kc;
        if (c < 2688) {
            int tn = c / 24; kc = c % 24;
            int n0 = tn * 16;
            dst = (u16*)(ws + OFF_WF) + c * 512;
            if (n0 < 512)       { src = Wq; ld = 512;  cn0 = n0; }
            else if (n0 < 1024) { src = Wk; ld = 512;  cn0 = n0 - 512; }
            else                { src = Wv; ld = CDIM; cn0 = n0 - 1024; }
        } else {
            int c2 = c - 2688;
            int tn = c2 / 24; kc = c2 % 24;
            dst = (u16*)(ws + OFF_WOF) + c2 * 512;
            src = Wout; ld = CDIM; cn0 = tn * 16;
        }
        int f = probe_f32(src);
        int nn = L & 15, kq = L >> 4;
        int base = (kc * 32 + kq * 8) * ld + cn0 + nn;
        union { u16 u[8]; uint4 v; } pk;
        if (f) {
            const float* sp = (const float*)src + base;
            float a0 = sp[0], a1 = sp[ld], a2 = sp[2 * ld], a3 = sp[3 * ld];
            float a4 = sp[4 * ld], a5 = sp[5 * ld], a6 = sp[6 * ld], a7 = sp[7 * ld];
            pk.u[0] = f2b(a0); pk.u[1] = f2b(a1); pk.u[2] = f2b(a2); pk.u[3] = f2b(a3);
            pk.u[4] = f2b(a4); pk.u[5] = f2b(a5); pk.u[6] = f2b(a6); pk.u[7] = f2b(a7);
        } else {
            const u16* sp = (const u16*)src + base;
            pk.u[0] = sp[0]; pk.u[1] = sp[ld]; pk.u[2] = sp[2 * ld]; pk.u[3] = sp[3 * ld];
            pk.u[4] = sp[4 * ld]; pk.u[5] = sp[5 * ld]; pk.u[6] = sp[6 * ld]; pk.u[7] = sp[7 * ld];
        }
        *(uint4*)(dst + L * 8) = pk.v;
        return;
    }
    // ---- wsuf ----
    int t = bx - 1104;
    int f = probe_f32(Wpos);
    for (int hd = tid; hd < 512; hd += 256) {
        float s0 = 0.f, s1 = 0.f, s2 = 0.f, s3 = 0.f;
        int f0 = t;
        for (; f0 + 4 <= NF; f0 += 4) {
            s0 += ldin(Wpos, f0 * 512 + hd, f);
            s1 += ldin(Wpos, (f0 + 1) * 512 + hd, f);
            s2 += ldin(Wpos, (f0 + 2) * 512 + hd, f);
            s3 += ldin(Wpos, (f0 + 3) * 512 + hd, f);
        }
        for (; f0 < NF; ++f0) s0 += ldin(Wpos, f0 * 512 + hd, f);
        ws[OFF_WSUF + t * 512 + hd] = (s0 + s1) + (s2 + s3);
    }
}

// ---------------------------------------------------------------------------
// Kernel 1: QKV GEMM, register-direct MFMA.  Q-block epilogue MFMA-based
// (validated R15): S11 = q_scaled . wsuf^T via 2 MFMAs; qf frag-structured.
// ---------------------------------------------------------------------------
__global__ __launch_bounds__(256) void qkv_reg(const void* __restrict__ rcb,
                                               const void* __restrict__ rpb,
                                               float* __restrict__ ws) {
    __shared__ float qt[64 * 68];
    __shared__ float rpd[12];
    const u16* xf = (const u16*)(ws + OFF_XF);
    const u16* wf = (const u16*)(ws + OFF_WF);
    u16* qf = (u16*)(ws + OFF_QF);
    u16* kf = (u16*)(ws + OFF_KF);
    u16* vf = (u16*)(ws + OFF_VF);

    int tid = threadIdx.x;
    int lane = tid & 63, w = tid >> 6;
    int quad = lane >> 4, col = lane & 15;
    int ti4 = blockIdx.x;
    int tn4 = blockIdx.y;
    int tn = tn4 * 4 + w;
    int i0 = ti4 * 64;
    bool isQ = (tn4 < 8);
    int hq = tn4;

    // Q-blocks: wsuf^T B-frags in registers (t = col, k = d)
    s16x8 bw0, bw1;
    int f32p = 0, f32c = 0;
    if (isQ) {
        f32p = probe_f32(rpb);
        f32c = probe_f32(rcb);
        int t = lane & 15, kq = lane >> 4;
        union { u16 u[8]; s16x8 v; } p0, p1;
#pragma unroll
        for (int j = 0; j < 8; ++j) {
            float v0 = 0.f, v1 = 0.f;
            if (t < 11) {
                v0 = ws[OFF_WSUF + t * 512 + hq * 64 + kq * 8 + j];
                v1 = ws[OFF_WSUF + t * 512 + hq * 64 + 32 + kq * 8 + j];
            }
            p0.u[j] = f2b(v0); p1.u[j] = f2b(v1);
        }
        bw0 = p0.v; bw1 = p1.v;
        if (tid < 12) {
            float s = 0.f;
            if (tid < 11) {
                const float* wp = ws + OFF_WSUF + tid * 512 + hq * 64;
                for (int d = 0; d < 64; ++d) s += ldin(rpb, hq * 64 + d, f32p) * wp[d];
            }
            rpd[tid] = s;
        }
    }

    f32x4 acc[4];
#pragma unroll
    for (int mt = 0; mt < 4; ++mt) acc[mt] = (f32x4){0.f, 0.f, 0.f, 0.f};

    const u16* bp = wf + (tn * 24) * 512 + lane * 8;
    const u16* ap = xf + (ti4 * 4 * 24) * 512 + lane * 8;
#pragma unroll 4
    for (int kc = 0; kc < 24; ++kc) {
        s16x8 bfrag = *(const s16x8*)(bp + kc * 512);
#pragma unroll
        for (int mt = 0; mt < 4; ++mt) {
            s16x8 afrag = *(const s16x8*)(ap + (mt * 24 + kc) * 512);
            acc[mt] = __builtin_amdgcn_mfma_f32_16x16x32_bf16(afrag, bfrag, acc[mt], 0, 0, 0);
        }
    }

    if (isQ) {
#pragma unroll
        for (int mt = 0; mt < 4; ++mt)
#pragma unroll
            for (int r = 0; r < 4; ++r)
                qt[(mt * 16 + quad * 4 + r) * 68 + w * 16 + col] = acc[mt][r] * 0.125f;
        __syncthreads();
        int m = lane & 15, kq = lane >> 4;
#pragma unroll
        for (int kc2 = 0; kc2 < 2; ++kc2) {
            union { u16 u[8]; uint4 v; } pk;
#pragma unroll
            for (int j = 0; j < 8; ++j) {
                int d = kc2 * 32 + kq * 8 + j;
                pk.u[j] = f2b(qt[(w * 16 + m) * 68 + d] + ldin(rcb, hq * 64 + d, f32c));
            }
            *(uint4*)(qf + (((hq * 96 + ti4 * 4 + w) * 2 + kc2) * 512) + lane * 8) = pk.v;
        }
        union { u16 u[8]; s16x8 v; } qa0, qa1;
#pragma unroll
        for (int j = 0; j < 8; ++j) {
            qa0.u[j] = f2b(qt[(w * 16 + m) * 68 + kq * 8 + j]);
            qa1.u[j] = f2b(qt[(w * 16 + m) * 68 + 32 + kq * 8 + j]);
        }
        f32x4 s11a = (f32x4){0.f, 0.f, 0.f, 0.f};
        s11a = __builtin_amdgcn_mfma_f32_16x16x32_bf16(qa0.v, bw0, s11a, 0, 0, 0);
        s11a = __builtin_amdgcn_mfma_f32_16x16x32_bf16(qa1.v, bw1, s11a, 0, 0, 0);
        if (col < 12) {
            float rp = rpd[col];
            float* s11 = ws + OFF_S11;
#pragma unroll
            for (int r = 0; r < 4; ++r)
                s11[(hq * NTOK + i0 + w * 16 + quad * 4 + r) * 12 + col] = s11a[r] + rp;
        }
    } else if (tn < 64) {
        int h = (tn >> 2) - 8;
        int d = ((tn & 3) * 16) + col;
#pragma unroll
        for (int mt = 0; mt < 4; ++mt) {
            int tj = ti4 * 4 + mt;
#pragma unroll
            for (int r = 0; r < 4; ++r) {
                int nn = quad * 4 + r;
                kf[((h * 96 + tj) * 2 + (d >> 5)) * 512 + FIDX(nn, d & 31)] = f2b(acc[mt][r]);
            }
        }
    } else {
        int c = tn * 16 + col - 1024;
        int h = c / 96, d = c % 96;
        int nt = d >> 4, nn = d & 15;
#pragma unroll
        for (int mt = 0; mt < 4; ++mt) {
#pragma unroll
            for (int r = 0; r < 4; ++r) {
                int j = i0 + mt * 16 + quad * 4 + r;
                int jc = j >> 5, kk = j & 31;
                vf[((h * 48 + jc) * 6 + nt) * 512 + FIDX(nn, kk)] = f2b(acc[mt][r]);
            }
        }
    }
}

// ---------------------------------------------------------------------------
// Kernel 3: MFMA flash attention.  8 waves/block, wave = 192 keys (6 chunks).
// No LDS fences (WAR: PV's lgkmcnt wait precedes next writes in program
// order; RAW: compiler-inserted wait via aliasing).  K-frags for chunk c+1
// prefetched during chunk c's softmax/PV (global/LDS don't alias -> legal).
// ---------------------------------------------------------------------------
__global__ __launch_bounds__(512) void attn_mfma(float* __restrict__ ws) {
    __shared__ float s11b[192];
    __shared__ alignas(16) u16 pbuf[8][16 * 36];
    __shared__ float Om[8][16 * 96];
    __shared__ float lw[8][16];

    const u16* qf = (const u16*)(ws + OFF_QF);
    const u16* kf = (const u16*)(ws + OFF_KF);
    const u16* vf = (const u16*)(ws + OFF_VF);
    const float* s11 = ws + OFF_S11;
    u16* aof = (u16*)(ws + OFF_AOF);

    int h = blockIdx.x & 7;               // XCD-affine
    int ti = blockIdx.x >> 3;
    int i0 = ti * 16;
    int tid = threadIdx.x;
    int wv = tid >> 6, lane = tid & 63;
    int quad = lane >> 4, col = lane & 15;

    if (tid < 192) s11b[tid] = s11[(h * NTOK + i0 + tid / 12) * 12 + tid % 12];
    const u16* qp = qf + ((h * 96 + ti) * 2) * 512 + lane * 8;
    s16x8 a_lo = *(const s16x8*)(qp);
    s16x8 a_hi = *(const s16x8*)(qp + 512);
    __syncthreads();

    f32x4 O[6];
    float lsum[4];
#pragma unroll
    for (int nt = 0; nt < 6; ++nt) O[nt] = (f32x4){0.f, 0.f, 0.f, 0.f};
#pragma unroll
    for (int r = 0; r < 4; ++r) lsum[r] = 0.f;

    // prefetch chunk 0 K-frags
    const u16* kbase = kf + ((h * 96 + wv * 12) * 2) * 512 + lane * 8;
    s16x8 k0lo = *(const s16x8*)(kbase);
    s16x8 k0hi = *(const s16x8*)(kbase + 512);
    s16x8 k1lo = *(const s16x8*)(kbase + 1024);
    s16x8 k1hi = *(const s16x8*)(kbase + 1536);

    for (int c = 0; c < 6; ++c) {
        // ---- QK^T with current K regs ----
        f32x4 t0 = (f32x4){0.f, 0.f, 0.f, 0.f};
        f32x4 t1 = (f32x4){0.f, 0.f, 0.f, 0.f};
        t0 = __builtin_amdgcn_mfma_f32_16x16x32_bf16(a_lo, k0lo, t0, 0, 0, 0);
        t0 = __builtin_amdgcn_mfma_f32_16x16x32_bf16(a_hi, k0hi, t0, 0, 0, 0);
        t1 = __builtin_amdgcn_mfma_f32_16x16x32_bf16(a_lo, k1lo, t1, 0, 0, 0);
        t1 = __builtin_amdgcn_mfma_f32_16x16x32_bf16(a_hi, k1hi, t1, 0, 0, 0);
        // ---- prefetch next chunk's K frags (independent; hides latency) ----
        if (c < 5) {
            const u16* kn = kbase + (c + 1) * 2048;
            k0lo = *(const s16x8*)(kn);
            k0hi = *(const s16x8*)(kn + 512);
            k1lo = *(const s16x8*)(kn + 1024);
            k1hi = *(const s16x8*)(kn + 1536);
        }
        // ---- bias + exp(s-12) + store P ----
        int j0 = wv * 192 + c * 32;
        int lo1 = j0 - (i0 + 15), lo2 = i0 - (j0 + 31);
        int dmin = lo1 > 0 ? lo1 : (lo2 > 0 ? lo2 : 0);
        int dm1 = i0 + 15 - j0, dm2 = j0 + 31 - i0;
        int dmax = dm1 > dm2 ? dm1 : dm2;
        int tlo = 31 - __builtin_clz(dmin + 1);
        int thi = 31 - __builtin_clz(dmax + 1);
        if (tlo == thi) {
#pragma unroll
            for (int r = 0; r < 4; ++r) {
                int row = quad * 4 + r;
                float bv = s11b[row * 12 + tlo] - 12.f;
                float p0 = __expf(t0[r] + bv);
                float p1 = __expf(t1[r] + bv);
                pbuf[wv][row * 36 + col] = f2b(p0);
                pbuf[wv][row * 36 + 16 + col] = f2b(p1);
                lsum[r] += p0 + p1;
            }
        } else {
#pragma unroll
            for (int r = 0; r < 4; ++r) {
                int row = quad * 4 + r;
                int ig = i0 + row;
                int d0 = ig - (j0 + col); d0 = d0 < 0 ? -d0 : d0;
                int d1 = ig - (j0 + 16 + col); d1 = d1 < 0 ? -d1 : d1;
                float v0 = t0[r] + s11b[row * 12 + (31 - __builtin_clz(d0 + 1))];
                float v1 = t1[r] + s11b[row * 12 + (31 - __builtin_clz(d1 + 1))];
                float p0 = __expf(v0 - 12.f);
                float p1 = __expf(v1 - 12.f);
                pbuf[wv][row * 36 + col] = f2b(p0);
                pbuf[wv][row * 36 + 16 + col] = f2b(p1);
                lsum[r] += p0 + p1;
            }
        }
        // ---- PV (compiler inserts lgkmcnt for the pbuf RAW) ----
        int jc = wv * 6 + c;
        const u16* pr = &pbuf[wv][col * 36 + quad * 8];
        union { s16x8 v; uint2 u2[2]; } pa;
        pa.u2[0] = *(const uint2*)(pr);
        pa.u2[1] = *(const uint2*)(pr + 4);
        const u16* vp = vf + ((h * 48 + jc) * 6) * 512 + lane * 8;
#pragma unroll
        for (int nt = 0; nt < 6; ++nt) {
            s16x8 vfr = *(const s16x8*)(vp + nt * 512);
            O[nt] = __builtin_amdgcn_mfma_f32_16x16x32_bf16(pa.v, vfr, O[nt], 0, 0, 0);
        }
    }

#pragma unroll
    for (int off = 1; off < 16; off <<= 1)
#pragma unroll
        for (int r = 0; r < 4; ++r) lsum[r] += __shfl_xor(lsum[r], off);
    if (col == 0)
#pragma unroll
        for (int r = 0; r < 4; ++r) lw[wv][quad * 4 + r] = lsum[r];
#pragma unroll
    for (int r = 0; r < 4; ++r) {
        int row = quad * 4 + r;
#pragma unroll
        for (int nt = 0; nt < 6; ++nt)
            Om[wv][row * 96 + nt * 16 + col] = O[nt][r];
    }
    __syncthreads();
    for (int idx = tid; idx < 16 * 96; idx += 512) {
        int row = idx / 96, cc = idx % 96;
        float L = 0.f, val = 0.f;
#pragma unroll
        for (int v = 0; v < 8; ++v) { L += lw[v][row]; val += Om[v][idx]; }
        aof[(ti * 24 + h * 3 + (cc >> 5)) * 512 + FIDX(row, cc & 31)] = f2b(val / L);
    }
}

// ---------------------------------------------------------------------------
// Kernel 4: output GEMM, register-direct MFMA, fragment-major + bias -> fp32.
// ---------------------------------------------------------------------------
__global__ __launch_bounds__(256) void out_reg(const void* __restrict__ bout,
                                               float* __restrict__ ws,
                                               float* __restrict__ out) {
    const u16* af = (const u16*)(ws + OFF_AOF);
    const u16* wof = (const u16*)(ws + OFF_WOF);
    int f32b = probe_f32(bout);

    int tid = threadIdx.x;
    int lane = tid & 63, w = tid >> 6;
    int quad = lane >> 4, col = lane & 15;
    int ti4 = blockIdx.x;
    int tn = blockIdx.y * 4 + w;
    int i0 = ti4 * 64;
    int n0 = blockIdx.y * 64;

    f32x4 acc[4];
#pragma unroll
    for (int mt = 0; mt < 4; ++mt) acc[mt] = (f32x4){0.f, 0.f, 0.f, 0.f};

    const u16* bp = wof + (tn * 24) * 512 + lane * 8;
    const u16* ap = af + (ti4 * 4 * 24) * 512 + lane * 8;
#pragma unroll 4
    for (int kc = 0; kc < 24; ++kc) {
        s16x8 bfrag = *(const s16x8*)(bp + kc * 512);
#pragma unroll
        for (int mt = 0; mt < 4; ++mt) {
            s16x8 afrag = *(const s16x8*)(ap + (mt * 24 + kc) * 512);
            acc[mt] = __builtin_amdgcn_mfma_f32_16x16x32_bf16(afrag, bfrag, acc[mt], 0, 0, 0);
        }
    }

    int c = n0 + w * 16 + col;
    float bias = ldin(bout, c, f32b);
#pragma unroll
    for (int mt = 0; mt < 4; ++mt) {
#pragma unroll
        for (int r = 0; r < 4; ++r) {
            int i = i0 + mt * 16 + quad * 4 + r;
            out[i * CDIM + c] = acc[mt][r] + bias;
        }
    }
}

// ---------------------------------------------------------------------------
extern "C" void kernel_launch(void* const* d_in, const int* in_sizes, int n_in,
                              void* d_out, int out_size, void* d_ws, size_t ws_size,
                              hipStream_t stream) {
    float* out = (float*)d_out;
    float* ws = (float*)d_ws;

    const int want[9] = {1179648, 393216, 393216, 589824, 589824, 768, 49152, 512, 512};
    int role2in[9], used[9] = {0};
    bool ok = (n_in == 9);
    if (ok) {
        for (int r = 0; r < 9; ++r) {
            int found = -1;
            for (int i = 0; i < 9 && found < 0; ++i)
                if (!used[i] && in_sizes[i] == want[r]) found = i;
            if (found < 0) { ok = false; break; }
            used[found] = 1;
            role2in[r] = found;
        }
    }
    if (!ok) for (int r = 0; r < 9; ++r) role2in[r] = r;

    const void* x    = d_in[role2in[0]];
    const void* Wq   = d_in[role2in[1]];
    const void* Wk   = d_in[role2in[2]];
    const void* Wv   = d_in[role2in[3]];
    const void* Wout = d_in[role2in[4]];
    const void* bout = d_in[role2in[5]];
    const void* Wpos = d_in[role2in[6]];
    const void* rcb  = d_in[role2in[7]];
    const void* rpb  = d_in[role2in[8]];

    hipLaunchKernelGGL(prep, dim3(1115), dim3(256), 0, stream,
                       x, Wq, Wk, Wv, Wout, Wpos, ws);
    hipLaunchKernelGGL(qkv_reg, dim3(24, 28), dim3(256), 0, stream,
                       rcb, rpb, ws);
    hipLaunchKernelGGL(attn_mfma, dim3(768), dim3(512), 0, stream, ws);
    hipLaunchKernelGGL(out_reg, dim3(24, 12), dim3(256), 0, stream,
                       bout, ws, out);
}